// Round 1
// baseline (6773.449 us; speedup 1.0000x reference)
//
#include <hip/hip_runtime.h>
#include <math.h>

// Problem constants
#define BDIM 64
#define NNODE 128
#define DLAT 80
#define NHEAD 8
#define DH 64
#define INNER 512
#define FFD 160
#define DEPTH 24
#define MROWS (BDIM * NNODE)   // 8192

// ---------------------------------------------------------------------------
// Kernel 1: graph structural bias  bias[b,i,j]
// ---------------------------------------------------------------------------
__global__ __launch_bounds__(256) void bias_kernel(
    const int* __restrict__ spp,        // [B,N,N]
    const int* __restrict__ ei,         // [B,N,N,20,3]
    const float* __restrict__ edge_emb, // [64]
    const float* __restrict__ edw,      // [40] (use first 20)
    const float* __restrict__ sp_emb,   // [40]
    float* __restrict__ biasb)          // [B,N,N]
{
    __shared__ float ee[64], ew[20], se[40];
    int tid = threadIdx.x;
    if (tid < 64) ee[tid] = edge_emb[tid];
    if (tid < 20) ew[tid] = edw[tid];
    if (tid < 40) se[tid] = sp_emb[tid];
    __syncthreads();

    int idx = blockIdx.x * 256 + tid;   // < B*N*N
    int spv = spp[idx];
    float spb = se[spv];
    int sp = min(20, max(1, spv - 1));

    const int4* p = (const int4*)(ei + (size_t)idx * 60);
    int e[60];
#pragma unroll
    for (int t = 0; t < 15; ++t) {
        int4 v = p[t];
        e[4*t+0] = v.x; e[4*t+1] = v.y; e[4*t+2] = v.z; e[4*t+3] = v.w;
    }
    float acc = 0.f;
#pragma unroll
    for (int m = 0; m < 20; ++m) {
        float s = ee[e[3*m]] + ee[e[3*m+1]] + ee[e[3*m+2]];
        acc += s * ew[m];
    }
    biasb[idx] = acc * (1.0f/3.0f) / (float)sp + spb;
}

// ---------------------------------------------------------------------------
// Kernel 2: node embeddings  x[b,n,:] = atom[xn] + indeg[ind] + outdeg[outd]
// ---------------------------------------------------------------------------
__global__ __launch_bounds__(256) void node_emb_kernel(
    const int* __restrict__ xn, const int* __restrict__ ind, const int* __restrict__ outd,
    const float* __restrict__ ae, const float* __restrict__ ie, const float* __restrict__ oe,
    float* __restrict__ x)
{
    int idx = blockIdx.x * 256 + threadIdx.x;   // < 8192*80
    int e = idx / DLAT, d = idx % DLAT;
    x[idx] = ae[xn[e]*DLAT + d] + ie[ind[e]*DLAT + d] + oe[outd[e]*DLAT + d];
}

// ---------------------------------------------------------------------------
// Generic fp32 GEMM:  out[M,N] = f( LN?(X)[M,K] @ W[K,N] + bias ) (+resid)
// BM=32, BN=128, BK=128, 256 threads, thread tile 2x8.
// LN path requires K <= BK (true: K=80).
// All N used here are multiples of 8 -> vector guards are all-or-nothing.
// ---------------------------------------------------------------------------
#define GBM 32
#define GBN 128
#define GBK 128

template<bool DO_LN, bool DO_GELU, bool DO_RESID>
__global__ __launch_bounds__(256) void gemm_kernel(
    const float* __restrict__ X,
    const float* __restrict__ lng, const float* __restrict__ lnb,
    const float* __restrict__ W,
    const float* __restrict__ bias,     // [N] or nullptr
    const float* __restrict__ resid,    // [M,N] or nullptr
    float* __restrict__ out,
    int M, int K, int N)
{
    __shared__ float xs[GBK][GBM + 4];   // [k][m]
    __shared__ float smean[GBM], srstd[GBM];

    int tid = threadIdx.x;
    int tx = tid & 15;          // col group (8 cols each)
    int ty = tid >> 4;          // row group (2 rows each)
    int m0 = blockIdx.y * GBM;
    int n0 = blockIdx.x * GBN + tx * 8;

    float acc[2][8];
#pragma unroll
    for (int i = 0; i < 2; ++i)
#pragma unroll
        for (int j = 0; j < 8; ++j) acc[i][j] = 0.f;

    for (int k0 = 0; k0 < K; k0 += GBK) {
        int bk = min(GBK, K - k0);
        int bk4 = bk >> 2;
        int nq = GBM * bk4;
        // stage X tile (transposed into LDS)
        for (int idx = tid; idx < nq; idx += 256) {
            int kq = idx % bk4;
            int m  = idx / bk4;
            float4 v = *(const float4*)(X + (size_t)(m0 + m) * K + k0 + kq * 4);
            xs[kq*4+0][m] = v.x; xs[kq*4+1][m] = v.y;
            xs[kq*4+2][m] = v.z; xs[kq*4+3][m] = v.w;
        }
        __syncthreads();

        if (DO_LN) {
            // K==bk (single tile). 8 threads per row.
            int row = tid >> 3, sub = tid & 7;
            float s = 0.f;
            for (int k = sub; k < K; k += 8) s += xs[k][row];
            s += __shfl_xor(s, 1); s += __shfl_xor(s, 2); s += __shfl_xor(s, 4);
            float mean = s / (float)K;
            float v = 0.f;
            for (int k = sub; k < K; k += 8) { float d = xs[k][row] - mean; v += d * d; }
            v += __shfl_xor(v, 1); v += __shfl_xor(v, 2); v += __shfl_xor(v, 4);
            float rstd = 1.0f / sqrtf(v / (float)K + 1e-5f);
            if (sub == 0) { smean[row] = mean; srstd[row] = rstd; }
            __syncthreads();
            for (int idx = tid; idx < K * GBM; idx += 256) {
                int m = idx & (GBM - 1);
                int k = idx >> 5;
                xs[k][m] = (xs[k][m] - smean[m]) * srstd[m] * lng[k] + lnb[k];
            }
            __syncthreads();
        }

        const float* wp = W + (size_t)k0 * N;
        bool col_ok = (n0 + 7) < N;
#pragma unroll 4
        for (int k = 0; k < bk; ++k) {
            float2 a = *(const float2*)&xs[k][ty * 2];
            float4 b0, b1;
            if (col_ok) {
                const float* wr = wp + (size_t)k * N + n0;
                b0 = *(const float4*)wr;
                b1 = *(const float4*)(wr + 4);
            } else {
                b0 = make_float4(0,0,0,0); b1 = make_float4(0,0,0,0);
            }
            float bv[8] = {b0.x,b0.y,b0.z,b0.w,b1.x,b1.y,b1.z,b1.w};
            float av[2] = {a.x, a.y};
#pragma unroll
            for (int i = 0; i < 2; ++i)
#pragma unroll
                for (int j = 0; j < 8; ++j) acc[i][j] += av[i] * bv[j];
        }
        __syncthreads();
    }

    // epilogue
    if (n0 + 7 < N) {
        float bv[8];
        if (bias) {
#pragma unroll
            for (int j = 0; j < 8; ++j) bv[j] = bias[n0 + j];
        } else {
#pragma unroll
            for (int j = 0; j < 8; ++j) bv[j] = 0.f;
        }
#pragma unroll
        for (int i = 0; i < 2; ++i) {
            int row = m0 + ty * 2 + i;
            float v[8];
#pragma unroll
            for (int j = 0; j < 8; ++j) v[j] = acc[i][j] + bv[j];
            if (DO_GELU) {
#pragma unroll
                for (int j = 0; j < 8; ++j)
                    v[j] = 0.5f * v[j] * (1.0f + erff(v[j] * 0.70710678118654752f));
            }
            if (DO_RESID) {
                const float* rp = resid + (size_t)row * N + n0;
                float4 r0 = *(const float4*)rp;
                float4 r1 = *(const float4*)(rp + 4);
                v[0]+=r0.x; v[1]+=r0.y; v[2]+=r0.z; v[3]+=r0.w;
                v[4]+=r1.x; v[5]+=r1.y; v[6]+=r1.z; v[7]+=r1.w;
            }
            float* op = out + (size_t)row * N + n0;
            *(float4*)op       = make_float4(v[0],v[1],v[2],v[3]);
            *(float4*)(op + 4) = make_float4(v[4],v[5],v[6],v[7]);
        }
    }
}

// ---------------------------------------------------------------------------
// Attention: per (b,h), i-half of 64 rows per block. 256 threads.
// Phase 1: sim = Q K^T * scale + bias; softmax (regs). Phase 2: P@V.
// ---------------------------------------------------------------------------
__global__ __launch_bounds__(256) void attn_kernel(
    const float* __restrict__ q,     // [B*N, 512] col h*64+d
    const float* __restrict__ kv,    // [B*N, 1024] k: h*64+d, v: 512+h*64+d
    const float* __restrict__ biasb, // [B,N,N]
    float* __restrict__ o)           // [B*N, 512]
{
    __shared__ float smem[12800];                      // 51.2 KB
    float (*qt)[68]  = (float(*)[68])smem;             // 64*68  = 4352
    float (*kt)[132] = (float(*)[132])(smem + 4352);   // 64*132 = 8448
    float (*pt)[69]  = (float(*)[69])smem;             // 128*69 = 8832 (aliases qt/kt)
    float* rsum      = smem + 8832;                    // 64

    int tid = threadIdx.x;
    int tx = tid & 15, ty = tid >> 4;
    int bh = blockIdx.y;
    int b = bh >> 3, h = bh & 7;
    int ib = blockIdx.x * 64;

    // stage Q (64 rows) and K (128 rows), transposed: [d][i], [d][j]
    const float* qbase = q + ((size_t)(b * NNODE + ib)) * INNER + h * DH;
    for (int idx = tid; idx < 64 * 64; idx += 256) {
        int i = idx >> 6, d = idx & 63;
        qt[d][i] = qbase[(size_t)i * INNER + d];
    }
    const float* kbase = kv + (size_t)b * NNODE * 1024 + h * DH;
    for (int idx = tid; idx < 128 * 64; idx += 256) {
        int j = idx >> 6, d = idx & 63;
        kt[d][j] = kbase[(size_t)j * 1024 + d];
    }
    __syncthreads();

    float acc[4][8];
#pragma unroll
    for (int i = 0; i < 4; ++i)
#pragma unroll
        for (int j = 0; j < 8; ++j) acc[i][j] = 0.f;

#pragma unroll 4
    for (int d = 0; d < 64; ++d) {
        float4 a  = *(const float4*)&qt[d][ty * 4];
        float4 b0 = *(const float4*)&kt[d][tx * 8];
        float4 b1 = *(const float4*)&kt[d][tx * 8 + 4];
        float av[4] = {a.x, a.y, a.z, a.w};
        float bv[8] = {b0.x,b0.y,b0.z,b0.w,b1.x,b1.y,b1.z,b1.w};
#pragma unroll
        for (int i = 0; i < 4; ++i)
#pragma unroll
            for (int j = 0; j < 8; ++j) acc[i][j] += av[i] * bv[j];
    }

    // bias + scale + softmax (row groups: 16 lanes share a row)
    float p[4][8];
    float rs[4];
#pragma unroll
    for (int ii = 0; ii < 4; ++ii) {
        int i = ib + ty * 4 + ii;
        const float* bp = biasb + ((size_t)b * NNODE + i) * NNODE + tx * 8;
        float4 c0 = *(const float4*)bp;
        float4 c1 = *(const float4*)(bp + 4);
        float cv[8] = {c0.x,c0.y,c0.z,c0.w,c1.x,c1.y,c1.z,c1.w};
        float s[8];
#pragma unroll
        for (int j = 0; j < 8; ++j) s[j] = acc[ii][j] * 0.125f + cv[j];
        float mx = s[0];
#pragma unroll
        for (int j = 1; j < 8; ++j) mx = fmaxf(mx, s[j]);
        mx = fmaxf(mx, __shfl_xor(mx, 1));
        mx = fmaxf(mx, __shfl_xor(mx, 2));
        mx = fmaxf(mx, __shfl_xor(mx, 4));
        mx = fmaxf(mx, __shfl_xor(mx, 8));
        float sum = 0.f;
#pragma unroll
        for (int j = 0; j < 8; ++j) { p[ii][j] = expf(s[j] - mx); sum += p[ii][j]; }
        sum += __shfl_xor(sum, 1);
        sum += __shfl_xor(sum, 2);
        sum += __shfl_xor(sum, 4);
        sum += __shfl_xor(sum, 8);
        rs[ii] = sum;
    }

    __syncthreads();   // all qt/kt reads done before aliasing pt writes

#pragma unroll
    for (int ii = 0; ii < 4; ++ii)
#pragma unroll
        for (int jj = 0; jj < 8; ++jj) pt[tx * 8 + jj][ty * 4 + ii] = p[ii][jj];
    if (tx == 0) {
#pragma unroll
        for (int ii = 0; ii < 4; ++ii) rsum[ty * 4 + ii] = rs[ii];
    }
    __syncthreads();

    // P @ V  (V streamed from global; d = tx*4 .. +3)
    float acc2[4][4];
#pragma unroll
    for (int i = 0; i < 4; ++i)
#pragma unroll
        for (int j = 0; j < 4; ++j) acc2[i][j] = 0.f;

    const float* vbase = kv + (size_t)b * NNODE * 1024 + INNER + h * DH + tx * 4;
#pragma unroll 4
    for (int j = 0; j < 128; ++j) {
        float4 vv = *(const float4*)(vbase + (size_t)j * 1024);
        float vvv[4] = {vv.x, vv.y, vv.z, vv.w};
        float pv[4];
#pragma unroll
        for (int ii = 0; ii < 4; ++ii) pv[ii] = pt[j][ty * 4 + ii];
#pragma unroll
        for (int ii = 0; ii < 4; ++ii)
#pragma unroll
            for (int dd = 0; dd < 4; ++dd) acc2[ii][dd] += pv[ii] * vvv[dd];
    }

#pragma unroll
    for (int ii = 0; ii < 4; ++ii) {
        int i = ib + ty * 4 + ii;
        float inv = 1.0f / rsum[ty * 4 + ii];
        float4 ov = make_float4(acc2[ii][0]*inv, acc2[ii][1]*inv,
                                acc2[ii][2]*inv, acc2[ii][3]*inv);
        *(float4*)(o + ((size_t)(b * NNODE + i)) * INNER + h * DH + tx * 4) = ov;
    }
}

// ---------------------------------------------------------------------------
// Final: mean over nodes -> LN -> @Wf + bf  => out[B]
// ---------------------------------------------------------------------------
__global__ __launch_bounds__(128) void final_kernel(
    const float* __restrict__ x, const float* __restrict__ g, const float* __restrict__ bta,
    const float* __restrict__ Wf, const float* __restrict__ bf, float* __restrict__ out)
{
    int bb = blockIdx.x;
    int t = threadIdx.x;
    __shared__ float pd[DLAT];
    __shared__ float red[2];
    __shared__ float rbuf[128];

    if (t < DLAT) {
        float s = 0.f;
        for (int n = 0; n < NNODE; ++n) s += x[((size_t)bb * NNODE + n) * DLAT + t];
        pd[t] = s * (1.0f / NNODE);
    }
    __syncthreads();
    if (t == 0) {
        float m = 0.f;
        for (int k = 0; k < DLAT; ++k) m += pd[k];
        m /= DLAT;
        float v = 0.f;
        for (int k = 0; k < DLAT; ++k) { float d = pd[k] - m; v += d * d; }
        v /= DLAT;
        red[0] = m; red[1] = 1.0f / sqrtf(v + 1e-5f);
    }
    __syncthreads();
    float contrib = 0.f;
    if (t < DLAT)
        contrib = ((pd[t] - red[0]) * red[1] * g[t] + bta[t]) * Wf[t];
    rbuf[t] = contrib;
    __syncthreads();
    if (t == 0) {
        float s = 0.f;
        for (int k = 0; k < DLAT; ++k) s += rbuf[k];
        out[bb] = s + bf[0];
    }
}

// ---------------------------------------------------------------------------
extern "C" void kernel_launch(void* const* d_in, const int* in_sizes, int n_in,
                              void* d_out, int out_size, void* d_ws, size_t ws_size,
                              hipStream_t stream)
{
    const int*   spatial_pos = (const int*)  d_in[0];
    const int*   edge_input  = (const int*)  d_in[1];
    const int*   x_nodes     = (const int*)  d_in[2];
    const int*   indeg       = (const int*)  d_in[3];
    const int*   outdeg      = (const int*)  d_in[4];
    const float* atom_emb    = (const float*)d_in[5];
    const float* indeg_emb   = (const float*)d_in[6];
    const float* outdeg_emb  = (const float*)d_in[7];
    const float* edge_emb    = (const float*)d_in[8];
    const float* edge_dis_w  = (const float*)d_in[9];
    const float* spatial_emb = (const float*)d_in[10];
    const float* ln1_g = (const float*)d_in[11];
    const float* ln1_b = (const float*)d_in[12];
    const float* Wq    = (const float*)d_in[13];
    const float* Wkv   = (const float*)d_in[14];
    const float* Wo    = (const float*)d_in[15];
    const float* bo    = (const float*)d_in[16];
    const float* ln2_g = (const float*)d_in[17];
    const float* ln2_b = (const float*)d_in[18];
    const float* W1    = (const float*)d_in[19];
    const float* b1    = (const float*)d_in[20];
    const float* W2    = (const float*)d_in[21];
    const float* b2    = (const float*)d_in[22];
    const float* lnf_g = (const float*)d_in[23];
    const float* lnf_b = (const float*)d_in[24];
    const float* Wf    = (const float*)d_in[25];
    const float* bf    = (const float*)d_in[26];

    float* ws = (float*)d_ws;
    // workspace layout (floats): total ~19.8M floats = 79.2 MB
    float* biasb = ws;                               // 1,048,576
    float* x     = biasb + (size_t)BDIM*NNODE*NNODE; //   655,360
    float* q     = x     + (size_t)MROWS*DLAT;       // 4,194,304
    float* kv    = q     + (size_t)MROWS*INNER;      // 8,388,608
    float* obuf  = kv    + (size_t)MROWS*2*INNER;    // 4,194,304
    float* ffh   = obuf  + (size_t)MROWS*INNER;      // 1,310,720

    bias_kernel<<<4096, 256, 0, stream>>>(spatial_pos, edge_input, edge_emb,
                                          edge_dis_w, spatial_emb, biasb);
    node_emb_kernel<<<2560, 256, 0, stream>>>(x_nodes, indeg, outdeg,
                                              atom_emb, indeg_emb, outdeg_emb, x);

    for (int L = 0; L < DEPTH; ++L) {
        const float* g1 = ln1_g + L*DLAT;
        const float* be1 = ln1_b + L*DLAT;
        // Q = LN1(x) @ Wq
        gemm_kernel<true,false,false><<<dim3(4,256), 256, 0, stream>>>(
            x, g1, be1, Wq + (size_t)L*DLAT*INNER, nullptr, nullptr, q,
            MROWS, DLAT, INNER);
        // KV = LN1(x) @ Wkv
        gemm_kernel<true,false,false><<<dim3(8,256), 256, 0, stream>>>(
            x, g1, be1, Wkv + (size_t)L*DLAT*2*INNER, nullptr, nullptr, kv,
            MROWS, DLAT, 2*INNER);
        // attention
        attn_kernel<<<dim3(2, BDIM*NHEAD), 256, 0, stream>>>(q, kv, biasb, obuf);
        // x = o @ Wo + bo + x
        gemm_kernel<false,false,true><<<dim3(1,256), 256, 0, stream>>>(
            obuf, nullptr, nullptr, Wo + (size_t)L*INNER*DLAT, bo + L*DLAT, x, x,
            MROWS, INNER, DLAT);
        // ffh = gelu(LN2(x) @ W1 + b1)
        gemm_kernel<true,true,false><<<dim3(2,256), 256, 0, stream>>>(
            x, ln2_g + L*DLAT, ln2_b + L*DLAT, W1 + (size_t)L*DLAT*FFD,
            b1 + L*FFD, nullptr, ffh, MROWS, DLAT, FFD);
        // x = ffh @ W2 + b2 + x
        gemm_kernel<false,false,true><<<dim3(1,256), 256, 0, stream>>>(
            ffh, nullptr, nullptr, W2 + (size_t)L*FFD*DLAT, b2 + L*DLAT, x, x,
            MROWS, FFD, DLAT);
    }

    final_kernel<<<BDIM, 128, 0, stream>>>(x, lnf_g, lnf_b, Wf, bf, (float*)d_out);
}

// Round 2
// 2368.831 us; speedup vs baseline: 2.8594x; 2.8594x over previous
//
#include <hip/hip_runtime.h>
#include <math.h>

#define BDIM 64
#define NNODE 128
#define DLAT 80
#define NHEAD 8
#define DH 64
#define INNER 512
#define FFD 160
#define DEPTH 24
#define MROWS (BDIM * NNODE)   // 8192

using bf16x8 = __attribute__((ext_vector_type(8))) short;
using f32x4  = __attribute__((ext_vector_type(4))) float;

#define MFMA(a, b, c) __builtin_amdgcn_mfma_f32_16x16x32_bf16((a), (b), (c), 0, 0, 0)

static __device__ __forceinline__ short f2bf(float f) {
    union { float f; unsigned u; } v; v.f = f;
    unsigned r = v.u + 0x7fffu + ((v.u >> 16) & 1u);   // RNE
    return (short)(r >> 16);
}

// ---------------------------------------------------------------------------
// Weight convert + transpose: out[l][n][k] = bf16(in[l][k][n])
// grid: (ceil(N/64), ceil(K/64), L), 256 threads
// ---------------------------------------------------------------------------
__global__ __launch_bounds__(256) void wconv_kernel(
    const float* __restrict__ in, short* __restrict__ out, int K, int N)
{
    __shared__ float t[64][65];
    int L = blockIdx.z;
    const float* src = in + (size_t)L * K * N;
    short* dst = out + (size_t)L * K * N;
    int n0 = blockIdx.x * 64, k0 = blockIdx.y * 64;
    int tx = threadIdx.x & 63, ty = threadIdx.x >> 6;
    for (int ki = ty; ki < 64; ki += 4) {
        int k = k0 + ki, n = n0 + tx;
        t[ki][tx] = (k < K && n < N) ? src[(size_t)k * N + n] : 0.f;
    }
    __syncthreads();
    for (int ni = ty; ni < 64; ni += 4) {
        int n = n0 + ni, k = k0 + tx;
        if (n < N && k < K) dst[(size_t)n * K + k] = f2bf(t[tx][ni]);
    }
}

// ---------------------------------------------------------------------------
// Graph structural bias
// ---------------------------------------------------------------------------
__global__ __launch_bounds__(256) void bias_kernel(
    const int* __restrict__ spp, const int* __restrict__ ei,
    const float* __restrict__ edge_emb, const float* __restrict__ edw,
    const float* __restrict__ sp_emb, float* __restrict__ biasb)
{
    __shared__ float ee[64], ew[20], se[40];
    int tid = threadIdx.x;
    if (tid < 64) ee[tid] = edge_emb[tid];
    if (tid < 20) ew[tid] = edw[tid];
    if (tid < 40) se[tid] = sp_emb[tid];
    __syncthreads();

    int idx = blockIdx.x * 256 + tid;
    int spv = spp[idx];
    float spb = se[spv];
    int sp = min(20, max(1, spv - 1));

    const int4* p = (const int4*)(ei + (size_t)idx * 60);
    int e[60];
#pragma unroll
    for (int t = 0; t < 15; ++t) {
        int4 v = p[t];
        e[4*t+0] = v.x; e[4*t+1] = v.y; e[4*t+2] = v.z; e[4*t+3] = v.w;
    }
    float acc = 0.f;
#pragma unroll
    for (int m = 0; m < 20; ++m) {
        float s = ee[e[3*m]] + ee[e[3*m+1]] + ee[e[3*m+2]];
        acc += s * ew[m];
    }
    biasb[idx] = acc * (1.0f/3.0f) / (float)sp + spb;
}

// ---------------------------------------------------------------------------
// Node embeddings
// ---------------------------------------------------------------------------
__global__ __launch_bounds__(256) void node_emb_kernel(
    const int* __restrict__ xn, const int* __restrict__ ind, const int* __restrict__ outd,
    const float* __restrict__ ae, const float* __restrict__ ie, const float* __restrict__ oe,
    float* __restrict__ x)
{
    int idx = blockIdx.x * 256 + threadIdx.x;
    int e = idx / DLAT, d = idx % DLAT;
    x[idx] = ae[xn[e]*DLAT + d] + ie[ind[e]*DLAT + d] + oe[outd[e]*DLAT + d];
}

// ---------------------------------------------------------------------------
// Fused LN1 + QKV GEMM (MFMA). BM=64, BN=128, K=80 (pad 96).
// bx 0-3: Q cols -> q_buf; 4-7: K cols -> k_buf; 8-11: V cols -> vt_buf (transposed)
// ---------------------------------------------------------------------------
__global__ __launch_bounds__(256) void qkv_kernel(
    const float* __restrict__ x, const float* __restrict__ g1, const float* __restrict__ b1v,
    const short* __restrict__ Wq_tL, const short* __restrict__ Wkv_tL,
    short* __restrict__ q_buf, short* __restrict__ k_buf, short* __restrict__ vt_buf)
{
    __shared__ short as_[64*104];
    __shared__ short bts[128*104];
    __shared__ float gb[160];
    int tid = threadIdx.x;
    int bx = blockIdx.x;
    int m0 = blockIdx.y * 64;

    if (tid < 160) gb[tid] = (tid < 80) ? g1[tid] : b1v[tid - 80];

    // LN: 4 threads per row, 20 elems each (5 float4)
    int row = tid >> 2, sub = tid & 3;
    const float* xr = x + (size_t)(m0 + row) * DLAT + sub * 20;
    float4 v0 = *(const float4*)(xr + 0);
    float4 v1 = *(const float4*)(xr + 4);
    float4 v2 = *(const float4*)(xr + 8);
    float4 v3 = *(const float4*)(xr + 12);
    float4 v4 = *(const float4*)(xr + 16);
    float s = v0.x+v0.y+v0.z+v0.w + v1.x+v1.y+v1.z+v1.w + v2.x+v2.y+v2.z+v2.w
            + v3.x+v3.y+v3.z+v3.w + v4.x+v4.y+v4.z+v4.w;
    s += __shfl_xor(s, 1); s += __shfl_xor(s, 2);
    float mean = s * 0.0125f;
    float var = 0.f;
    {
        float d;
        d=v0.x-mean; var+=d*d; d=v0.y-mean; var+=d*d; d=v0.z-mean; var+=d*d; d=v0.w-mean; var+=d*d;
        d=v1.x-mean; var+=d*d; d=v1.y-mean; var+=d*d; d=v1.z-mean; var+=d*d; d=v1.w-mean; var+=d*d;
        d=v2.x-mean; var+=d*d; d=v2.y-mean; var+=d*d; d=v2.z-mean; var+=d*d; d=v2.w-mean; var+=d*d;
        d=v3.x-mean; var+=d*d; d=v3.y-mean; var+=d*d; d=v3.z-mean; var+=d*d; d=v3.w-mean; var+=d*d;
        d=v4.x-mean; var+=d*d; d=v4.y-mean; var+=d*d; d=v4.z-mean; var+=d*d; d=v4.w-mean; var+=d*d;
    }
    var += __shfl_xor(var, 1); var += __shfl_xor(var, 2);
    float rstd = 1.0f / sqrtf(var * 0.0125f + 1e-5f);

    // stage B^T tile (zero-pad k>=80)
    const short* wb; int nbase;
    if (bx < 4) { wb = Wq_tL;  nbase = bx * 128; }
    else        { wb = Wkv_tL; nbase = bx * 128 - 512; }
    for (int idx = tid; idx < 128*12; idx += 256) {
        int n = idx / 12, seg = idx % 12, k = seg * 8;
        uint4 val = make_uint4(0,0,0,0);
        if (k < 80) val = *(const uint4*)(wb + (size_t)(nbase + n) * 80 + k);
        *(uint4*)(bts + n*104 + k) = val;
    }
    __syncthreads();   // gb ready, bts staged

    // write normalized bf16 A tile + zero pad
    {
        short* ar = as_ + row*104 + sub*20;
        const float4* gv = (const float4*)(gb + sub*20);
        const float4* bv = (const float4*)(gb + 80 + sub*20);
        float4 vv[5] = {v0,v1,v2,v3,v4};
#pragma unroll
        for (int qq = 0; qq < 5; ++qq) {
            float4 g4 = gv[qq], b4 = bv[qq], v = vv[qq];
            short4 o;
            o.x = f2bf((v.x-mean)*rstd*g4.x + b4.x);
            o.y = f2bf((v.y-mean)*rstd*g4.y + b4.y);
            o.z = f2bf((v.z-mean)*rstd*g4.z + b4.z);
            o.w = f2bf((v.w-mean)*rstd*g4.w + b4.w);
            *(short4*)(ar + qq*4) = o;
        }
        short4 z4; z4.x = z4.y = z4.z = z4.w = 0;
        *(short4*)(as_ + row*104 + 80 + sub*4) = z4;
    }
    __syncthreads();

    int lane = tid & 63;
    int w = tid >> 6, wm = w >> 1, wn = w & 1;
    int l15 = lane & 15, lk = lane >> 4;

    f32x4 acc[2][4] = {};
#pragma unroll
    for (int ss = 0; ss < 3; ++ss) {
        int kb = ss*32 + lk*8;
        bf16x8 a0 = *(const bf16x8*)(as_ + (wm*32 + l15)*104 + kb);
        bf16x8 a1 = *(const bf16x8*)(as_ + (wm*32 + 16 + l15)*104 + kb);
#pragma unroll
        for (int j = 0; j < 4; ++j) {
            bf16x8 bv = *(const bf16x8*)(bts + (wn*64 + j*16 + l15)*104 + kb);
            acc[0][j] = MFMA(a0, bv, acc[0][j]);
            acc[1][j] = MFMA(a1, bv, acc[1][j]);
        }
    }

    int colbase = bx*128 + wn*64 + l15;
    int rowbase = m0 + wm*32 + lk*4;
    if (bx < 8) {
        short* dstbuf = (bx < 4) ? q_buf : k_buf;
        int cb = (bx < 4) ? colbase : colbase - 512;
#pragma unroll
        for (int fi = 0; fi < 2; ++fi)
#pragma unroll
        for (int j = 0; j < 4; ++j)
#pragma unroll
        for (int r = 0; r < 4; ++r)
            dstbuf[(size_t)(rowbase + fi*16 + r) * INNER + cb + j*16] = f2bf(acc[fi][j][r]);
    } else {
#pragma unroll
        for (int fi = 0; fi < 2; ++fi)
#pragma unroll
        for (int j = 0; j < 4; ++j) {
            int c = colbase - 1024 + j*16;
            int h = c >> 6, d = c & 63;
            int m = rowbase + fi*16;
            int bI = m >> 7, jn = m & 127;
            short4 sv;
            sv.x = f2bf(acc[fi][j][0]); sv.y = f2bf(acc[fi][j][1]);
            sv.z = f2bf(acc[fi][j][2]); sv.w = f2bf(acc[fi][j][3]);
            *(short4*)(vt_buf + (size_t)((bI*8 + h)*64 + d) * 128 + jn) = sv;
        }
    }
}

// ---------------------------------------------------------------------------
// Attention per (b,h): QK^T (MFMA) -> softmax (regs) -> PV (MFMA)
// ---------------------------------------------------------------------------
__global__ __launch_bounds__(256) void attn_kernel(
    const short* __restrict__ q_buf, const short* __restrict__ k_buf,
    const short* __restrict__ vt_buf, const float* __restrict__ biasb,
    short* __restrict__ obuf)
{
    __shared__ short smem[27136];
    short* qs  = smem;                 // [128][72]
    short* ks  = smem + 9216;          // [128][72]
    short* vts = smem + 18432;         // [64][136]
    short* ps  = smem;                 // [128][136] aliases qs/ks

    int tid = threadIdx.x;
    int bh = blockIdx.x;
    int bI = bh >> 3, h = bh & 7;

    {   // stage Q, K: [node][d]
        int i = tid >> 1, seg = tid & 1;
        const short* qg = q_buf + (size_t)(bI*128 + i)*INNER + h*64 + seg*32;
        const short* kg = k_buf + (size_t)(bI*128 + i)*INNER + h*64 + seg*32;
        short* qd = qs + i*72 + seg*32;
        short* kd = ks + i*72 + seg*32;
#pragma unroll
        for (int qq = 0; qq < 4; ++qq) {
            *(uint4*)(qd + qq*8) = *(const uint4*)(qg + qq*8);
            *(uint4*)(kd + qq*8) = *(const uint4*)(kg + qq*8);
        }
    }
    {   // stage V^T: [d][node]
        int d = tid >> 2, seg = tid & 3;
        const short* vg = vt_buf + (size_t)((bI*8 + h)*64 + d)*128 + seg*32;
        short* vd = vts + d*136 + seg*32;
#pragma unroll
        for (int qq = 0; qq < 4; ++qq)
            *(uint4*)(vd + qq*8) = *(const uint4*)(vg + qq*8);
    }
    __syncthreads();

    int lane = tid & 63, w = tid >> 6;
    int l15 = lane & 15, lk = lane >> 4;
    int r0 = w * 32;

    f32x4 acc[2][8] = {};
#pragma unroll
    for (int ss = 0; ss < 2; ++ss) {
        int kb = ss*32 + lk*8;
        bf16x8 a0 = *(const bf16x8*)(qs + (r0 + l15)*72 + kb);
        bf16x8 a1 = *(const bf16x8*)(qs + (r0 + 16 + l15)*72 + kb);
#pragma unroll
        for (int j = 0; j < 8; ++j) {
            bf16x8 bv = *(const bf16x8*)(ks + (j*16 + l15)*72 + kb);
            acc[0][j] = MFMA(a0, bv, acc[0][j]);
            acc[1][j] = MFMA(a1, bv, acc[1][j]);
        }
    }

    // softmax (rows owned per lane: r = r0 + fi*16 + lk*4 + reg)
    float pv[2][8][4];
    float rinv[2][4];
    const float* bbase = biasb + (size_t)bI * NNODE * NNODE;
#pragma unroll
    for (int fi = 0; fi < 2; ++fi)
#pragma unroll
    for (int r = 0; r < 4; ++r) {
        int i = r0 + fi*16 + lk*4 + r;
        const float* bp = bbase + (size_t)i * NNODE + l15;
        float sv[8];
#pragma unroll
        for (int j = 0; j < 8; ++j) sv[j] = acc[fi][j][r] * 0.125f + bp[j*16];
        float mx = sv[0];
#pragma unroll
        for (int j = 1; j < 8; ++j) mx = fmaxf(mx, sv[j]);
        mx = fmaxf(mx, __shfl_xor(mx, 1));
        mx = fmaxf(mx, __shfl_xor(mx, 2));
        mx = fmaxf(mx, __shfl_xor(mx, 4));
        mx = fmaxf(mx, __shfl_xor(mx, 8));
        float sum = 0.f;
#pragma unroll
        for (int j = 0; j < 8; ++j) { float e = __expf(sv[j] - mx); pv[fi][j][r] = e; sum += e; }
        sum += __shfl_xor(sum, 1);
        sum += __shfl_xor(sum, 2);
        sum += __shfl_xor(sum, 4);
        sum += __shfl_xor(sum, 8);
        rinv[fi][r] = 1.0f / sum;
    }
    __syncthreads();   // all QK LDS reads complete before aliasing writes

#pragma unroll
    for (int fi = 0; fi < 2; ++fi)
#pragma unroll
    for (int r = 0; r < 4; ++r) {
        int i = r0 + fi*16 + lk*4 + r;
#pragma unroll
        for (int j = 0; j < 8; ++j)
            ps[i*136 + j*16 + l15] = f2bf(pv[fi][j][r]);
    }
    __syncthreads();

    // PV
    f32x4 acc2[2][4] = {};
#pragma unroll
    for (int ss = 0; ss < 4; ++ss) {
        int kb = ss*32 + lk*8;
        bf16x8 a0 = *(const bf16x8*)(ps + (r0 + l15)*136 + kb);
        bf16x8 a1 = *(const bf16x8*)(ps + (r0 + 16 + l15)*136 + kb);
#pragma unroll
        for (int fd = 0; fd < 4; ++fd) {
            bf16x8 bv = *(const bf16x8*)(vts + (fd*16 + l15)*136 + kb);
            acc2[0][fd] = MFMA(a0, bv, acc2[0][fd]);
            acc2[1][fd] = MFMA(a1, bv, acc2[1][fd]);
        }
    }

#pragma unroll
    for (int fi = 0; fi < 2; ++fi)
#pragma unroll
    for (int fd = 0; fd < 4; ++fd)
#pragma unroll
    for (int r = 0; r < 4; ++r) {
        int i = r0 + fi*16 + lk*4 + r;
        obuf[(size_t)(bI*128 + i) * INNER + h*64 + fd*16 + l15] =
            f2bf(acc2[fi][fd][r] * rinv[fi][r]);
    }
}

// ---------------------------------------------------------------------------
// O-projection: x += obuf @ Wo (+ bo). BM=128, N=80, split-K z=4 (BK=64 x2)
// ---------------------------------------------------------------------------
__global__ __launch_bounds__(256) void oproj_kernel(
    const short* __restrict__ obuf, const short* __restrict__ Wo_tL,
    const float* __restrict__ boL, float* __restrict__ x)
{
    __shared__ short as_[128*72];
    __shared__ short bts[80*72];
    int tid = threadIdx.x;
    int m0 = blockIdx.x * 128;
    int z = blockIdx.y;
    int lane = tid & 63, w = tid >> 6, l15 = lane & 15, lk = lane >> 4;

    f32x4 acc[2][5] = {};
    for (int kk = 0; kk < 2; ++kk) {
        int k0 = z*128 + kk*64;
        if (kk) __syncthreads();
        {
            int row = tid >> 1, seg = tid & 1;
            const short* src = obuf + (size_t)(m0 + row)*INNER + k0 + seg*32;
            short* dstp = as_ + row*72 + seg*32;
#pragma unroll
            for (int qq = 0; qq < 4; ++qq)
                *(uint4*)(dstp + qq*8) = *(const uint4*)(src + qq*8);
        }
        for (int idx = tid; idx < 640; idx += 256) {
            int n = idx >> 3, seg = idx & 7;
            *(uint4*)(bts + n*72 + seg*8) =
                *(const uint4*)(Wo_tL + (size_t)n*INNER + k0 + seg*8);
        }
        __syncthreads();
#pragma unroll
        for (int ss = 0; ss < 2; ++ss) {
            int kb = ss*32 + lk*8;
            bf16x8 a0 = *(const bf16x8*)(as_ + (w*32 + l15)*72 + kb);
            bf16x8 a1 = *(const bf16x8*)(as_ + (w*32 + 16 + l15)*72 + kb);
#pragma unroll
            for (int fj = 0; fj < 5; ++fj) {
                bf16x8 bv = *(const bf16x8*)(bts + (fj*16 + l15)*72 + kb);
                acc[0][fj] = MFMA(a0, bv, acc[0][fj]);
                acc[1][fj] = MFMA(a1, bv, acc[1][fj]);
            }
        }
    }
#pragma unroll
    for (int fi = 0; fi < 2; ++fi)
#pragma unroll
    for (int fj = 0; fj < 5; ++fj)
#pragma unroll
    for (int r = 0; r < 4; ++r) {
        int m = m0 + w*32 + fi*16 + lk*4 + r;
        int n = fj*16 + l15;
        float v = acc[fi][fj][r];
        if (z == 0) v += boL[n];
        atomicAdd(&x[(size_t)m*DLAT + n], v);
    }
}

// ---------------------------------------------------------------------------
// FF1: ffh = gelu(LN2(x) @ W1 + b1). BM=32, N=160, K=80(pad 96)
// ---------------------------------------------------------------------------
__global__ __launch_bounds__(256) void ff1_kernel(
    const float* __restrict__ x, const float* __restrict__ g2, const float* __restrict__ b2v,
    const short* __restrict__ W1_tL, const float* __restrict__ bb1L,
    short* __restrict__ ffh)
{
    __shared__ short as_[32*104];
    __shared__ short bts[160*104];
    __shared__ float gb[160];
    int tid = threadIdx.x;
    int m0 = blockIdx.x * 32;

    if (tid < 160) gb[tid] = (tid < 80) ? g2[tid] : b2v[tid - 80];

    // LN: 8 threads/row
    int row = tid >> 3, sub = tid & 7;
    const float* xr = x + (size_t)(m0 + row) * DLAT;
    float4 va = *(const float4*)(xr + sub*4);
    float4 vb = *(const float4*)(xr + 32 + sub*4);
    float4 vc = make_float4(0,0,0,0);
    bool has3 = sub < 4;
    if (has3) vc = *(const float4*)(xr + 64 + sub*4);
    float s = va.x+va.y+va.z+va.w + vb.x+vb.y+vb.z+vb.w + vc.x+vc.y+vc.z+vc.w;
    s += __shfl_xor(s, 1); s += __shfl_xor(s, 2); s += __shfl_xor(s, 4);
    float mean = s * 0.0125f;
    float var = 0.f;
    {
        float d;
        d=va.x-mean; var+=d*d; d=va.y-mean; var+=d*d; d=va.z-mean; var+=d*d; d=va.w-mean; var+=d*d;
        d=vb.x-mean; var+=d*d; d=vb.y-mean; var+=d*d; d=vb.z-mean; var+=d*d; d=vb.w-mean; var+=d*d;
        if (has3) { d=vc.x-mean; var+=d*d; d=vc.y-mean; var+=d*d; d=vc.z-mean; var+=d*d; d=vc.w-mean; var+=d*d; }
    }
    var += __shfl_xor(var, 1); var += __shfl_xor(var, 2); var += __shfl_xor(var, 4);
    float rstd = 1.0f / sqrtf(var * 0.0125f + 1e-5f);

    for (int idx = tid; idx < 160*12; idx += 256) {
        int n = idx / 12, seg = idx % 12, k = seg * 8;
        uint4 val = make_uint4(0,0,0,0);
        if (k < 80) val = *(const uint4*)(W1_tL + (size_t)n * 80 + k);
        *(uint4*)(bts + n*104 + k) = val;
    }
    __syncthreads();

    {
        float4 g4, b4; short4 o;
        int k = sub*4;
        g4 = *(const float4*)(gb + k); b4 = *(const float4*)(gb + 80 + k);
        o.x = f2bf((va.x-mean)*rstd*g4.x + b4.x);
        o.y = f2bf((va.y-mean)*rstd*g4.y + b4.y);
        o.z = f2bf((va.z-mean)*rstd*g4.z + b4.z);
        o.w = f2bf((va.w-mean)*rstd*g4.w + b4.w);
        *(short4*)(as_ + row*104 + k) = o;
        k = 32 + sub*4;
        g4 = *(const float4*)(gb + k); b4 = *(const float4*)(gb + 80 + k);
        o.x = f2bf((vb.x-mean)*rstd*g4.x + b4.x);
        o.y = f2bf((vb.y-mean)*rstd*g4.y + b4.y);
        o.z = f2bf((vb.z-mean)*rstd*g4.z + b4.z);
        o.w = f2bf((vb.w-mean)*rstd*g4.w + b4.w);
        *(short4*)(as_ + row*104 + k) = o;
        if (has3) {
            k = 64 + sub*4;
            g4 = *(const float4*)(gb + k); b4 = *(const float4*)(gb + 80 + k);
            o.x = f2bf((vc.x-mean)*rstd*g4.x + b4.x);
            o.y = f2bf((vc.y-mean)*rstd*g4.y + b4.y);
            o.z = f2bf((vc.z-mean)*rstd*g4.z + b4.z);
            o.w = f2bf((vc.w-mean)*rstd*g4.w + b4.w);
            *(short4*)(as_ + row*104 + k) = o;
        } else {
            short4 z4; z4.x = z4.y = z4.z = z4.w = 0;
            *(short4*)(as_ + row*104 + 80 + (sub-4)*4) = z4;
        }
    }
    __syncthreads();

    int lane = tid & 63, w = tid >> 6, l15 = lane & 15, lk = lane >> 4;
    int wr = (w >> 1) * 16, wc = (w & 1) * 80;

    f32x4 acc[5] = {};
#pragma unroll
    for (int ss = 0; ss < 3; ++ss) {
        int kb = ss*32 + lk*8;
        bf16x8 a = *(const bf16x8*)(as_ + (wr + l15)*104 + kb);
#pragma unroll
        for (int fj = 0; fj < 5; ++fj) {
            bf16x8 bv = *(const bf16x8*)(bts + (wc + fj*16 + l15)*104 + kb);
            acc[fj] = MFMA(a, bv, acc[fj]);
        }
    }
#pragma unroll
    for (int fj = 0; fj < 5; ++fj)
#pragma unroll
    for (int r = 0; r < 4; ++r) {
        int m = m0 + wr + lk*4 + r;
        int c = wc + fj*16 + l15;
        float v = acc[fj][r] + bb1L[c];
        v = 0.5f * v * (1.0f + erff(v * 0.70710678118654752f));
        ffh[(size_t)m * FFD + c] = f2bf(v);
    }
}

// ---------------------------------------------------------------------------
// FF2: x += ffh @ W2 (+ b2). BM=64, N=80, K=160 split-K z=2 (96 each, pad)
// ---------------------------------------------------------------------------
__global__ __launch_bounds__(256) void ff2_kernel(
    const short* __restrict__ ffh, const short* __restrict__ W2_tL,
    const float* __restrict__ bb2L, float* __restrict__ x)
{
    __shared__ short as_[64*104];
    __shared__ short bts[80*104];
    int tid = threadIdx.x;
    int m0 = blockIdx.x * 64;
    int z = blockIdx.y;
    int k0 = z * 96;

    for (int idx = tid; idx < 64*12; idx += 256) {
        int row = idx / 12, seg = idx % 12, k = k0 + seg*8;
        uint4 v = make_uint4(0,0,0,0);
        if (k < 160) v = *(const uint4*)(ffh + (size_t)(m0+row)*FFD + k);
        *(uint4*)(as_ + row*104 + seg*8) = v;
    }
    for (int idx = tid; idx < 80*12; idx += 256) {
        int n = idx / 12, seg = idx % 12, k = k0 + seg*8;
        uint4 v = make_uint4(0,0,0,0);
        if (k < 160) v = *(const uint4*)(W2_tL + (size_t)n*FFD + k);
        *(uint4*)(bts + n*104 + seg*8) = v;
    }
    __syncthreads();

    int lane = tid & 63, w = tid >> 6, l15 = lane & 15, lk = lane >> 4;
    f32x4 acc[5] = {};
#pragma unroll
    for (int ss = 0; ss < 3; ++ss) {
        int kb = ss*32 + lk*8;
        bf16x8 a = *(const bf16x8*)(as_ + (w*16 + l15)*104 + kb);
#pragma unroll
        for (int fj = 0; fj < 5; ++fj) {
            bf16x8 bv = *(const bf16x8*)(bts + (fj*16 + l15)*104 + kb);
            acc[fj] = MFMA(a, bv, acc[fj]);
        }
    }
#pragma unroll
    for (int fj = 0; fj < 5; ++fj)
#pragma unroll
    for (int r = 0; r < 4; ++r) {
        int m = m0 + w*16 + lk*4 + r;
        int n = fj*16 + l15;
        float v = acc[fj][r];
        if (z == 0) v += bb2L[n];
        atomicAdd(&x[(size_t)m*DLAT + n], v);
    }
}

// ---------------------------------------------------------------------------
// Final: mean over nodes -> LN -> @Wf + bf
// ---------------------------------------------------------------------------
__global__ __launch_bounds__(128) void final_kernel(
    const float* __restrict__ x, const float* __restrict__ g, const float* __restrict__ bta,
    const float* __restrict__ Wf, const float* __restrict__ bf, float* __restrict__ out)
{
    int bb = blockIdx.x;
    int t = threadIdx.x;
    __shared__ float pd[DLAT];
    __shared__ float red[2];
    __shared__ float rbuf[128];

    if (t < DLAT) {
        float s = 0.f;
        for (int n = 0; n < NNODE; ++n) s += x[((size_t)bb * NNODE + n) * DLAT + t];
        pd[t] = s * (1.0f / NNODE);
    }
    __syncthreads();
    if (t == 0) {
        float m = 0.f;
        for (int k = 0; k < DLAT; ++k) m += pd[k];
        m /= DLAT;
        float v = 0.f;
        for (int k = 0; k < DLAT; ++k) { float d = pd[k] - m; v += d * d; }
        v /= DLAT;
        red[0] = m; red[1] = 1.0f / sqrtf(v + 1e-5f);
    }
    __syncthreads();
    float contrib = 0.f;
    if (t < DLAT)
        contrib = ((pd[t] - red[0]) * red[1] * g[t] + bta[t]) * Wf[t];
    rbuf[t] = contrib;
    __syncthreads();
    if (t == 0) {
        float s = 0.f;
        for (int k = 0; k < DLAT; ++k) s += rbuf[k];
        out[bb] = s + bf[0];
    }
}

// ---------------------------------------------------------------------------
extern "C" void kernel_launch(void* const* d_in, const int* in_sizes, int n_in,
                              void* d_out, int out_size, void* d_ws, size_t ws_size,
                              hipStream_t stream)
{
    const int*   spatial_pos = (const int*)  d_in[0];
    const int*   edge_input  = (const int*)  d_in[1];
    const int*   x_nodes     = (const int*)  d_in[2];
    const int*   indeg       = (const int*)  d_in[3];
    const int*   outdeg      = (const int*)  d_in[4];
    const float* atom_emb    = (const float*)d_in[5];
    const float* indeg_emb   = (const float*)d_in[6];
    const float* outdeg_emb  = (const float*)d_in[7];
    const float* edge_emb    = (const float*)d_in[8];
    const float* edge_dis_w  = (const float*)d_in[9];
    const float* spatial_emb = (const float*)d_in[10];
    const float* ln1_g = (const float*)d_in[11];
    const float* ln1_b = (const float*)d_in[12];
    const float* Wq    = (const float*)d_in[13];
    const float* Wkv   = (const float*)d_in[14];
    const float* Wo    = (const float*)d_in[15];
    const float* bo    = (const float*)d_in[16];
    const float* ln2_g = (const float*)d_in[17];
    const float* ln2_b = (const float*)d_in[18];
    const float* W1    = (const float*)d_in[19];
    const float* b1    = (const float*)d_in[20];
    const float* W2    = (const float*)d_in[21];
    const float* b2    = (const float*)d_in[22];
    const float* lnf_g = (const float*)d_in[23];
    const float* lnf_b = (const float*)d_in[24];
    const float* Wf    = (const float*)d_in[25];
    const float* bf    = (const float*)d_in[26];

    char* wsb = (char*)d_ws;
    float* biasb  = (float*)(wsb + 0);          //  4,194,304 B
    float* x      = (float*)(wsb + 4194304);    //  2,621,440 B
    short* q_buf  = (short*)(wsb + 6815744);    //  8,388,608 B
    short* k_buf  = (short*)(wsb + 15204352);   //  8,388,608 B
    short* vt_buf = (short*)(wsb + 23592960);   //  8,388,608 B
    short* obuf   = (short*)(wsb + 31981568);   //  8,388,608 B
    short* ffh    = (short*)(wsb + 40370176);   //  2,621,440 B
    short* Wq_t   = (short*)(wsb + 42991616);   //  1,966,080 B
    short* Wkv_t  = (short*)(wsb + 44957696);   //  3,932,160 B
    short* Wo_t   = (short*)(wsb + 48889856);   //  1,966,080 B
    short* W1_t   = (short*)(wsb + 50855936);   //    614,400 B
    short* W2_t   = (short*)(wsb + 51470336);   //    614,400 B

    wconv_kernel<<<dim3(8, 2, 24), 256, 0, stream>>>(Wq,  Wq_t,  80, 512);
    wconv_kernel<<<dim3(16, 2, 24), 256, 0, stream>>>(Wkv, Wkv_t, 80, 1024);
    wconv_kernel<<<dim3(2, 8, 24), 256, 0, stream>>>(Wo,  Wo_t,  512, 80);
    wconv_kernel<<<dim3(3, 2, 24), 256, 0, stream>>>(W1,  W1_t,  80, 160);
    wconv_kernel<<<dim3(2, 3, 24), 256, 0, stream>>>(W2,  W2_t,  160, 80);

    bias_kernel<<<4096, 256, 0, stream>>>(spatial_pos, edge_input, edge_emb,
                                          edge_dis_w, spatial_emb, biasb);
    node_emb_kernel<<<2560, 256, 0, stream>>>(x_nodes, indeg, outdeg,
                                              atom_emb, indeg_emb, outdeg_emb, x);

    for (int L = 0; L < DEPTH; ++L) {
        qkv_kernel<<<dim3(12, 128), 256, 0, stream>>>(
            x, ln1_g + L*DLAT, ln1_b + L*DLAT,
            Wq_t + (size_t)L*DLAT*INNER, Wkv_t + (size_t)L*DLAT*2*INNER,
            q_buf, k_buf, vt_buf);
        attn_kernel<<<512, 256, 0, stream>>>(q_buf, k_buf, vt_buf, biasb, obuf);
        oproj_kernel<<<dim3(64, 4), 256, 0, stream>>>(
            obuf, Wo_t + (size_t)L*INNER*DLAT, bo + L*DLAT, x);
        ff1_kernel<<<256, 256, 0, stream>>>(
            x, ln2_g + L*DLAT, ln2_b + L*DLAT,
            W1_t + (size_t)L*DLAT*FFD, b1 + L*FFD, ffh);
        ff2_kernel<<<dim3(128, 2), 256, 0, stream>>>(
            ffh, W2_t + (size_t)L*FFD*DLAT, b2 + L*DLAT, x);
    }

    final_kernel<<<BDIM, 128, 0, stream>>>(x, lnf_g, lnf_b, Wf, bf, (float*)d_out);
}

// Round 3
// 2282.742 us; speedup vs baseline: 2.9672x; 1.0377x over previous
//
#include <hip/hip_runtime.h>
#include <math.h>

#define BDIM 64
#define NNODE 128
#define DLAT 80
#define NHEAD 8
#define DH 64
#define INNER 512
#define FFD 160
#define DEPTH 24
#define MROWS (BDIM * NNODE)   // 8192

using bf16x8 = __attribute__((ext_vector_type(8))) short;
using f32x4  = __attribute__((ext_vector_type(4))) float;

#define MFMA(a, b, c) __builtin_amdgcn_mfma_f32_16x16x32_bf16((a), (b), (c), 0, 0, 0)

static __device__ __forceinline__ short f2bf(float f) {
    union { float f; unsigned u; } v; v.f = f;
    unsigned r = v.u + 0x7fffu + ((v.u >> 16) & 1u);   // RNE
    return (short)(r >> 16);
}

// ---------------------------------------------------------------------------
// Weight convert + transpose: out[l][n][k] = bf16(in[l][k][n])
// ---------------------------------------------------------------------------
__global__ __launch_bounds__(256) void wconv_kernel(
    const float* __restrict__ in, short* __restrict__ out, int K, int N)
{
    __shared__ float t[64][65];
    int L = blockIdx.z;
    const float* src = in + (size_t)L * K * N;
    short* dst = out + (size_t)L * K * N;
    int n0 = blockIdx.x * 64, k0 = blockIdx.y * 64;
    int tx = threadIdx.x & 63, ty = threadIdx.x >> 6;
    for (int ki = ty; ki < 64; ki += 4) {
        int k = k0 + ki, n = n0 + tx;
        t[ki][tx] = (k < K && n < N) ? src[(size_t)k * N + n] : 0.f;
    }
    __syncthreads();
    for (int ni = ty; ni < 64; ni += 4) {
        int n = n0 + ni, k = k0 + tx;
        if (n < N && k < K) dst[(size_t)n * K + k] = f2bf(t[tx][ni]);
    }
}

// ---------------------------------------------------------------------------
// Graph structural bias
// ---------------------------------------------------------------------------
__global__ __launch_bounds__(256) void bias_kernel(
    const int* __restrict__ spp, const int* __restrict__ ei,
    const float* __restrict__ edge_emb, const float* __restrict__ edw,
    const float* __restrict__ sp_emb, float* __restrict__ biasb)
{
    __shared__ float ee[64], ew[20], se[40];
    int tid = threadIdx.x;
    if (tid < 64) ee[tid] = edge_emb[tid];
    if (tid < 20) ew[tid] = edw[tid];
    if (tid < 40) se[tid] = sp_emb[tid];
    __syncthreads();

    int idx = blockIdx.x * 256 + tid;
    int spv = spp[idx];
    float spb = se[spv];
    int sp = min(20, max(1, spv - 1));

    const int4* p = (const int4*)(ei + (size_t)idx * 60);
    int e[60];
#pragma unroll
    for (int t = 0; t < 15; ++t) {
        int4 v = p[t];
        e[4*t+0] = v.x; e[4*t+1] = v.y; e[4*t+2] = v.z; e[4*t+3] = v.w;
    }
    float acc = 0.f;
#pragma unroll
    for (int m = 0; m < 20; ++m) {
        float s = ee[e[3*m]] + ee[e[3*m+1]] + ee[e[3*m+2]];
        acc += s * ew[m];
    }
    biasb[idx] = acc * (1.0f/3.0f) / (float)sp + spb;
}

// ---------------------------------------------------------------------------
// Node embeddings
// ---------------------------------------------------------------------------
__global__ __launch_bounds__(256) void node_emb_kernel(
    const int* __restrict__ xn, const int* __restrict__ ind, const int* __restrict__ outd,
    const float* __restrict__ ae, const float* __restrict__ ie, const float* __restrict__ oe,
    float* __restrict__ x)
{
    int idx = blockIdx.x * 256 + threadIdx.x;
    int e = idx / DLAT, d = idx % DLAT;
    x[idx] = ae[xn[e]*DLAT + d] + ie[ind[e]*DLAT + d] + oe[outd[e]*DLAT + d];
}

// ---------------------------------------------------------------------------
// Whole-layer fused kernel. Grid 256 = (b, quarter). 256 threads = 4 waves.
// LDS (shorts):
//   lnx  @ 0      [128][104]  (13312)  bf16 LN1(x), k-pad 80..95 = 0
//   kh2  @ 13312  [128][136]  (17408)  K for head pair (j, dpair)
//   vth2 @ 30720  [128][136]  (17408)  V^T for head pair (dpair, j)
//   qh2  @ 48128  [32][136]   (4352)   Q own rows, head pair cols
//   ph2  @ 52480  [2][32][136](8704)   P bf16
//   obuf @ 61184  [32][520]   (16640)  attention out, all heads
// overlays (attn region dead after pair loop):
//   x_mid @ 0 (float[32][80]); h2 @ 13312 [32][104]; ffh @ 18432 [32][168]
// total 155,648 B dynamic LDS
// ---------------------------------------------------------------------------
__global__ __launch_bounds__(256, 1) void layer_kernel(
    const float* __restrict__ xin, float* __restrict__ xout,
    const float* __restrict__ biasb,
    const short* __restrict__ Wq_t, const short* __restrict__ Wkv_t,
    const short* __restrict__ Wo_t, const short* __restrict__ W1_t,
    const short* __restrict__ W2_t,
    const float* __restrict__ g1, const float* __restrict__ be1,
    const float* __restrict__ boL,
    const float* __restrict__ g2, const float* __restrict__ be2,
    const float* __restrict__ b1L, const float* __restrict__ b2L)
{
    extern __shared__ short smem[];
    short* lnx  = smem;             // [128][104]
    short* kh2  = smem + 13312;     // [128][136]
    short* vth2 = smem + 30720;     // [128][136]
    short* qh2  = smem + 48128;     // [32][136]
    short* ph2  = smem + 52480;     // [2][32][136]
    short* obuf = smem + 61184;     // [32][520]
    float* x_mid = (float*)smem;    // [32][80] overlay
    short* h2   = smem + 13312;     // [32][104] overlay
    short* ffh  = smem + 18432;     // [32][168] overlay

    int tid = threadIdx.x;
    int b = blockIdx.x >> 2, qq = blockIdx.x & 3;
    int R0 = qq * 32;
    const float* xb = xin + (size_t)b * NNODE * DLAT;

    // ---- LN1 for all 128 rows of b -> lnx bf16 ----
    {
        int row = tid >> 1, sub = tid & 1;
        const float* xr = xb + row * DLAT + sub * 40;
        float4 v[10];
#pragma unroll
        for (int i = 0; i < 10; ++i) v[i] = *(const float4*)(xr + i * 4);
        float s = 0.f;
#pragma unroll
        for (int i = 0; i < 10; ++i) s += v[i].x + v[i].y + v[i].z + v[i].w;
        s += __shfl_xor(s, 1);
        float mean = s * 0.0125f;
        float var = 0.f;
#pragma unroll
        for (int i = 0; i < 10; ++i) {
            float d;
            d = v[i].x - mean; var += d * d;
            d = v[i].y - mean; var += d * d;
            d = v[i].z - mean; var += d * d;
            d = v[i].w - mean; var += d * d;
        }
        var += __shfl_xor(var, 1);
        float rstd = 1.0f / sqrtf(var * 0.0125f + 1e-5f);
        short* dst = lnx + row * 104 + sub * 40;
#pragma unroll
        for (int i = 0; i < 10; ++i) {
            int c = sub * 40 + i * 4;
            float4 g4 = *(const float4*)(g1 + c);
            float4 b4 = *(const float4*)(be1 + c);
            short4 o;
            o.x = f2bf((v[i].x - mean) * rstd * g4.x + b4.x);
            o.y = f2bf((v[i].y - mean) * rstd * g4.y + b4.y);
            o.z = f2bf((v[i].z - mean) * rstd * g4.z + b4.z);
            o.w = f2bf((v[i].w - mean) * rstd * g4.w + b4.w);
            *(short4*)(dst + i * 4) = o;
        }
        short4 z4; z4.x = z4.y = z4.z = z4.w = 0;
        *(short4*)(lnx + row * 104 + 80 + sub * 8) = z4;
        *(short4*)(lnx + row * 104 + 84 + sub * 8) = z4;
    }

    int lane = tid & 63, w = tid >> 6;
    int l15 = lane & 15, lk = lane >> 4;

    // bias registers for softmax: rows R0 + (w&1)*16 + lk*4 + r, cols jf*16+l15
    float breg[4][8];
    {
        const float* bp = biasb + ((size_t)b * NNODE + R0 + (w & 1) * 16 + lk * 4) * NNODE + l15;
#pragma unroll
        for (int r = 0; r < 4; ++r)
#pragma unroll
            for (int jf = 0; jf < 8; ++jf)
                breg[r][jf] = bp[r * NNODE + jf * 16];
    }
    float rinv[4];
    __syncthreads();

    // ---- head pair loop ----
#pragma unroll 1
    for (int h0 = 0; h0 < 8; h0 += 2) {
        // --- phase 1: K, V (m-split, all 128 rows), Q (n-split, own 32 rows)
        {
            bf16x8 a[2][3];
#pragma unroll
            for (int mf = 0; mf < 2; ++mf)
#pragma unroll
                for (int ss = 0; ss < 3; ++ss)
                    a[mf][ss] = *(const bf16x8*)(lnx + (w * 32 + mf * 16 + l15) * 104 + lk * 8 + ss * 32);

            f32x4 accK[2][8] = {};
#pragma unroll
            for (int ss = 0; ss < 3; ++ss)
#pragma unroll
                for (int nf = 0; nf < 8; ++nf) {
                    bf16x8 bv = *(const bf16x8*)(Wkv_t + (size_t)(h0 * 64 + nf * 16 + l15) * DLAT + lk * 8 + ss * 32);
                    accK[0][nf] = MFMA(a[0][ss], bv, accK[0][nf]);
                    accK[1][nf] = MFMA(a[1][ss], bv, accK[1][nf]);
                }
#pragma unroll
            for (int mf = 0; mf < 2; ++mf)
#pragma unroll
                for (int nf = 0; nf < 8; ++nf)
#pragma unroll
                    for (int r = 0; r < 4; ++r)
                        kh2[(w * 32 + mf * 16 + lk * 4 + r) * 136 + nf * 16 + l15] = f2bf(accK[mf][nf][r]);

            f32x4 accV[2][8] = {};
#pragma unroll
            for (int ss = 0; ss < 3; ++ss)
#pragma unroll
                for (int nf = 0; nf < 8; ++nf) {
                    bf16x8 bv = *(const bf16x8*)(Wkv_t + (size_t)(INNER + h0 * 64 + nf * 16 + l15) * DLAT + lk * 8 + ss * 32);
                    accV[0][nf] = MFMA(a[0][ss], bv, accV[0][nf]);
                    accV[1][nf] = MFMA(a[1][ss], bv, accV[1][nf]);
                }
#pragma unroll
            for (int mf = 0; mf < 2; ++mf)
#pragma unroll
                for (int nf = 0; nf < 8; ++nf)
#pragma unroll
                    for (int r = 0; r < 4; ++r)
                        vth2[(nf * 16 + l15) * 136 + (w * 32 + mf * 16 + lk * 4 + r)] = f2bf(accV[mf][nf][r]);

            bf16x8 aq[2][3];
#pragma unroll
            for (int mf = 0; mf < 2; ++mf)
#pragma unroll
                for (int ss = 0; ss < 3; ++ss)
                    aq[mf][ss] = *(const bf16x8*)(lnx + (R0 + mf * 16 + l15) * 104 + lk * 8 + ss * 32);

            f32x4 accQ[2][2] = {};
#pragma unroll
            for (int ss = 0; ss < 3; ++ss)
#pragma unroll
                for (int q = 0; q < 2; ++q) {
                    bf16x8 bv = *(const bf16x8*)(Wq_t + (size_t)(h0 * 64 + (w * 2 + q) * 16 + l15) * DLAT + lk * 8 + ss * 32);
                    accQ[0][q] = MFMA(aq[0][ss], bv, accQ[0][q]);
                    accQ[1][q] = MFMA(aq[1][ss], bv, accQ[1][q]);
                }
#pragma unroll
            for (int mf = 0; mf < 2; ++mf)
#pragma unroll
                for (int q = 0; q < 2; ++q)
#pragma unroll
                    for (int r = 0; r < 4; ++r)
                        qh2[(mf * 16 + lk * 4 + r) * 136 + (w * 2 + q) * 16 + l15] = f2bf(accQ[mf][q][r]);
        }
        __syncthreads();

        // --- phase 2: QK^T + softmax. wave w: head hp = w>>1, mfrag = w&1
        {
            int hp = w >> 1, mf = w & 1;
            f32x4 acc[8] = {};
#pragma unroll
            for (int ss = 0; ss < 2; ++ss) {
                bf16x8 aa = *(const bf16x8*)(qh2 + (mf * 16 + l15) * 136 + hp * 64 + lk * 8 + ss * 32);
#pragma unroll
                for (int jf = 0; jf < 8; ++jf) {
                    bf16x8 bv = *(const bf16x8*)(kh2 + (jf * 16 + l15) * 136 + hp * 64 + lk * 8 + ss * 32);
                    acc[jf] = MFMA(aa, bv, acc[jf]);
                }
            }
#pragma unroll
            for (int r = 0; r < 4; ++r) {
                float sv[8];
#pragma unroll
                for (int jf = 0; jf < 8; ++jf) sv[jf] = acc[jf][r] * 0.125f + breg[r][jf];
                float mx = sv[0];
#pragma unroll
                for (int jf = 1; jf < 8; ++jf) mx = fmaxf(mx, sv[jf]);
                mx = fmaxf(mx, __shfl_xor(mx, 1));
                mx = fmaxf(mx, __shfl_xor(mx, 2));
                mx = fmaxf(mx, __shfl_xor(mx, 4));
                mx = fmaxf(mx, __shfl_xor(mx, 8));
                float e[8], sum = 0.f;
#pragma unroll
                for (int jf = 0; jf < 8; ++jf) { e[jf] = __expf(sv[jf] - mx); sum += e[jf]; }
                sum += __shfl_xor(sum, 1);
                sum += __shfl_xor(sum, 2);
                sum += __shfl_xor(sum, 4);
                sum += __shfl_xor(sum, 8);
                rinv[r] = 1.0f / sum;
#pragma unroll
                for (int jf = 0; jf < 8; ++jf)
                    ph2[(hp * 32 + mf * 16 + lk * 4 + r) * 136 + jf * 16 + l15] = f2bf(e[jf]);
            }
        }
        __syncthreads();

        // --- phase 3: P @ V^T
        {
            int hp = w >> 1, mf = w & 1;
            f32x4 acc[4] = {};
#pragma unroll
            for (int ks = 0; ks < 4; ++ks) {
                bf16x8 aa = *(const bf16x8*)(ph2 + (hp * 32 + mf * 16 + l15) * 136 + lk * 8 + ks * 32);
#pragma unroll
                for (int nf = 0; nf < 4; ++nf) {
                    bf16x8 bv = *(const bf16x8*)(vth2 + (hp * 64 + nf * 16 + l15) * 136 + lk * 8 + ks * 32);
                    acc[nf] = MFMA(aa, bv, acc[nf]);
                }
            }
#pragma unroll
            for (int nf = 0; nf < 4; ++nf)
#pragma unroll
                for (int r = 0; r < 4; ++r)
                    obuf[(mf * 16 + lk * 4 + r) * 520 + (h0 + hp) * 64 + nf * 16 + l15] =
                        f2bf(acc[nf][r] * rinv[r]);
        }
        __syncthreads();
    }

    // ---- O-projection + bias + residual -> x_mid (waves 0,1) ----
    if (w < 2) {
        f32x4 acc[5] = {};
#pragma unroll
        for (int ks = 0; ks < 16; ++ks) {
            bf16x8 aa = *(const bf16x8*)(obuf + (w * 16 + l15) * 520 + lk * 8 + ks * 32);
#pragma unroll
            for (int nf = 0; nf < 5; ++nf) {
                bf16x8 bv = *(const bf16x8*)(Wo_t + (size_t)(nf * 16 + l15) * INNER + lk * 8 + ks * 32);
                acc[nf] = MFMA(aa, bv, acc[nf]);
            }
        }
#pragma unroll
        for (int nf = 0; nf < 5; ++nf)
#pragma unroll
            for (int r = 0; r < 4; ++r) {
                int row = w * 16 + lk * 4 + r, n = nf * 16 + l15;
                x_mid[row * DLAT + n] = acc[nf][r] + boL[n] + xb[(size_t)(R0 + row) * DLAT + n];
            }
    }
    __syncthreads();

    // ---- LN2 -> h2 bf16 ----
    {
        int row = tid >> 3, sub = tid & 7;
        const float* xr = x_mid + row * DLAT;
        float4 va = *(const float4*)(xr + sub * 4);
        float4 vb = *(const float4*)(xr + 32 + sub * 4);
        float4 vc = make_float4(0, 0, 0, 0);
        bool has3 = sub < 4;
        if (has3) vc = *(const float4*)(xr + 64 + sub * 4);
        float s = va.x + va.y + va.z + va.w + vb.x + vb.y + vb.z + vb.w + vc.x + vc.y + vc.z + vc.w;
        s += __shfl_xor(s, 1); s += __shfl_xor(s, 2); s += __shfl_xor(s, 4);
        float mean = s * 0.0125f;
        float var = 0.f;
        {
            float d;
            d = va.x - mean; var += d * d; d = va.y - mean; var += d * d;
            d = va.z - mean; var += d * d; d = va.w - mean; var += d * d;
            d = vb.x - mean; var += d * d; d = vb.y - mean; var += d * d;
            d = vb.z - mean; var += d * d; d = vb.w - mean; var += d * d;
            if (has3) {
                d = vc.x - mean; var += d * d; d = vc.y - mean; var += d * d;
                d = vc.z - mean; var += d * d; d = vc.w - mean; var += d * d;
            }
        }
        var += __shfl_xor(var, 1); var += __shfl_xor(var, 2); var += __shfl_xor(var, 4);
        float rstd = 1.0f / sqrtf(var * 0.0125f + 1e-5f);

        float4 g4, b4; short4 o;
        int c = sub * 4;
        g4 = *(const float4*)(g2 + c); b4 = *(const float4*)(be2 + c);
        o.x = f2bf((va.x - mean) * rstd * g4.x + b4.x);
        o.y = f2bf((va.y - mean) * rstd * g4.y + b4.y);
        o.z = f2bf((va.z - mean) * rstd * g4.z + b4.z);
        o.w = f2bf((va.w - mean) * rstd * g4.w + b4.w);
        *(short4*)(h2 + row * 104 + c) = o;
        c = 32 + sub * 4;
        g4 = *(const float4*)(g2 + c); b4 = *(const float4*)(be2 + c);
        o.x = f2bf((vb.x - mean) * rstd * g4.x + b4.x);
        o.y = f2bf((vb.y - mean) * rstd * g4.y + b4.y);
        o.z = f2bf((vb.z - mean) * rstd * g4.z + b4.z);
        o.w = f2bf((vb.w - mean) * rstd * g4.w + b4.w);
        *(short4*)(h2 + row * 104 + c) = o;
        if (has3) {
            c = 64 + sub * 4;
            g4 = *(const float4*)(g2 + c); b4 = *(const float4*)(be2 + c);
            o.x = f2bf((vc.x - mean) * rstd * g4.x + b4.x);
            o.y = f2bf((vc.y - mean) * rstd * g4.y + b4.y);
            o.z = f2bf((vc.z - mean) * rstd * g4.z + b4.z);
            o.w = f2bf((vc.w - mean) * rstd * g4.w + b4.w);
            *(short4*)(h2 + row * 104 + c) = o;
        } else {
            short4 z4; z4.x = z4.y = z4.z = z4.w = 0;
            *(short4*)(h2 + row * 104 + 80 + (sub - 4) * 4) = z4;
        }
    }
    __syncthreads();

    // ---- FF1 + GELU -> ffh (4 waves: wm = w>>1 rows, wn = w&1 cols) ----
    {
        int wm = w >> 1, wn = w & 1;
        f32x4 acc[5] = {};
#pragma unroll
        for (int ss = 0; ss < 3; ++ss) {
            bf16x8 aa = *(const bf16x8*)(h2 + (wm * 16 + l15) * 104 + lk * 8 + ss * 32);
#pragma unroll
            for (int nf = 0; nf < 5; ++nf) {
                bf16x8 bv = *(const bf16x8*)(W1_t + (size_t)(wn * 80 + nf * 16 + l15) * DLAT + lk * 8 + ss * 32);
                acc[nf] = MFMA(aa, bv, acc[nf]);
            }
        }
#pragma unroll
        for (int nf = 0; nf < 5; ++nf)
#pragma unroll
            for (int r = 0; r < 4; ++r) {
                int c = wn * 80 + nf * 16 + l15;
                float v = acc[nf][r] + b1L[c];
                v = 0.5f * v * (1.0f + erff(v * 0.70710678118654752f));
                ffh[(wm * 16 + lk * 4 + r) * 168 + c] = f2bf(v);
            }
    }
    __syncthreads();

    // ---- FF2 + bias + residual -> xout (waves 0,1) ----
    if (w < 2) {
        f32x4 acc[5] = {};
#pragma unroll
        for (int ks = 0; ks < 5; ++ks) {
            bf16x8 aa = *(const bf16x8*)(ffh + (w * 16 + l15) * 168 + lk * 8 + ks * 32);
#pragma unroll
            for (int nf = 0; nf < 5; ++nf) {
                bf16x8 bv = *(const bf16x8*)(W2_t + (size_t)(nf * 16 + l15) * FFD + lk * 8 + ks * 32);
                acc[nf] = MFMA(aa, bv, acc[nf]);
            }
        }
#pragma unroll
        for (int nf = 0; nf < 5; ++nf)
#pragma unroll
            for (int r = 0; r < 4; ++r) {
                int row = w * 16 + lk * 4 + r, n = nf * 16 + l15;
                xout[((size_t)b * NNODE + R0 + row) * DLAT + n] =
                    acc[nf][r] + b2L[n] + x_mid[row * DLAT + n];
            }
    }
}

// ---------------------------------------------------------------------------
// Final: mean over nodes -> LN -> @Wf + bf
// ---------------------------------------------------------------------------
__global__ __launch_bounds__(128) void final_kernel(
    const float* __restrict__ x, const float* __restrict__ g, const float* __restrict__ bta,
    const float* __restrict__ Wf, const float* __restrict__ bf, float* __restrict__ out)
{
    int bb = blockIdx.x;
    int t = threadIdx.x;
    __shared__ float pd[DLAT];
    __shared__ float red[2];
    __shared__ float rbuf[128];

    if (t < DLAT) {
        float s = 0.f;
        for (int n = 0; n < NNODE; ++n) s += x[((size_t)bb * NNODE + n) * DLAT + t];
        pd[t] = s * (1.0f / NNODE);
    }
    __syncthreads();
    if (t == 0) {
        float m = 0.f;
        for (int k = 0; k < DLAT; ++k) m += pd[k];
        m /= DLAT;
        float v = 0.f;
        for (int k = 0; k < DLAT; ++k) { float d = pd[k] - m; v += d * d; }
        v /= DLAT;
        red[0] = m; red[1] = 1.0f / sqrtf(v + 1e-5f);
    }
    __syncthreads();
    float contrib = 0.f;
    if (t < DLAT)
        contrib = ((pd[t] - red[0]) * red[1] * g[t] + bta[t]) * Wf[t];
    rbuf[t] = contrib;
    __syncthreads();
    if (t == 0) {
        float s = 0.f;
        for (int k = 0; k < DLAT; ++k) s += rbuf[k];
        out[bb] = s + bf[0];
    }
}

// ---------------------------------------------------------------------------
extern "C" void kernel_launch(void* const* d_in, const int* in_sizes, int n_in,
                              void* d_out, int out_size, void* d_ws, size_t ws_size,
                              hipStream_t stream)
{
    const int*   spatial_pos = (const int*)  d_in[0];
    const int*   edge_input  = (const int*)  d_in[1];
    const int*   x_nodes     = (const int*)  d_in[2];
    const int*   indeg       = (const int*)  d_in[3];
    const int*   outdeg      = (const int*)  d_in[4];
    const float* atom_emb    = (const float*)d_in[5];
    const float* indeg_emb   = (const float*)d_in[6];
    const float* outdeg_emb  = (const float*)d_in[7];
    const float* edge_emb    = (const float*)d_in[8];
    const float* edge_dis_w  = (const float*)d_in[9];
    const float* spatial_emb = (const float*)d_in[10];
    const float* ln1_g = (const float*)d_in[11];
    const float* ln1_b = (const float*)d_in[12];
    const float* Wq    = (const float*)d_in[13];
    const float* Wkv   = (const float*)d_in[14];
    const float* Wo    = (const float*)d_in[15];
    const float* bo    = (const float*)d_in[16];
    const float* ln2_g = (const float*)d_in[17];
    const float* ln2_b = (const float*)d_in[18];
    const float* W1    = (const float*)d_in[19];
    const float* b1    = (const float*)d_in[20];
    const float* W2    = (const float*)d_in[21];
    const float* b2    = (const float*)d_in[22];
    const float* lnf_g = (const float*)d_in[23];
    const float* lnf_b = (const float*)d_in[24];
    const float* Wf    = (const float*)d_in[25];
    const float* bf    = (const float*)d_in[26];

    char* wsb = (char*)d_ws;
    float* biasb = (float*)(wsb + 0);           //  4,194,304 B
    float* x0    = (float*)(wsb + 4194304);     //  2,621,440 B
    float* x1    = (float*)(wsb + 6815744);     //  2,621,440 B
    short* Wq_t  = (short*)(wsb + 9437184);     //  1,966,080 B
    short* Wkv_t = (short*)(wsb + 11403264);    //  3,932,160 B
    short* Wo_t  = (short*)(wsb + 15335424);    //  1,966,080 B
    short* W1_t  = (short*)(wsb + 17301504);    //    614,400 B
    short* W2_t  = (short*)(wsb + 17915904);    //    614,400 B  (+slack beyond)

    static const int LDS_BYTES = 155648;
    hipFuncSetAttribute((const void*)layer_kernel,
                        hipFuncAttributeMaxDynamicSharedMemorySize, LDS_BYTES);

    wconv_kernel<<<dim3(8, 2, 24), 256, 0, stream>>>(Wq,  Wq_t,  80, 512);
    wconv_kernel<<<dim3(16, 2, 24), 256, 0, stream>>>(Wkv, Wkv_t, 80, 1024);
    wconv_kernel<<<dim3(2, 8, 24), 256, 0, stream>>>(Wo,  Wo_t,  512, 80);
    wconv_kernel<<<dim3(3, 2, 24), 256, 0, stream>>>(W1,  W1_t,  80, 160);
    wconv_kernel<<<dim3(2, 3, 24), 256, 0, stream>>>(W2,  W2_t,  160, 80);

    bias_kernel<<<4096, 256, 0, stream>>>(spatial_pos, edge_input, edge_emb,
                                          edge_dis_w, spatial_emb, biasb);
    node_emb_kernel<<<2560, 256, 0, stream>>>(x_nodes, indeg, outdeg,
                                              atom_emb, indeg_emb, outdeg_emb, x0);

    for (int L = 0; L < DEPTH; ++L) {
        const float* xin  = (L & 1) ? x1 : x0;
        float*       xout = (L & 1) ? x0 : x1;
        layer_kernel<<<256, 256, LDS_BYTES, stream>>>(
            xin, xout, biasb,
            Wq_t  + (size_t)L * DLAT * INNER,
            Wkv_t + (size_t)L * DLAT * 2 * INNER,
            Wo_t  + (size_t)L * INNER * DLAT,
            W1_t  + (size_t)L * DLAT * FFD,
            W2_t  + (size_t)L * FFD * DLAT,
            ln1_g + L * DLAT, ln1_b + L * DLAT,
            bo + L * DLAT,
            ln2_g + L * DLAT, ln2_b + L * DLAT,
            b1 + L * FFD, b2 + L * DLAT);
    }

    final_kernel<<<BDIM, 128, 0, stream>>>(x0, lnf_g, lnf_b, Wf, bf, (float*)d_out);
}

// Round 4
// 1521.413 us; speedup vs baseline: 4.4521x; 1.5004x over previous
//
#include <hip/hip_runtime.h>
#include <math.h>

#define BDIM 64
#define NNODE 128
#define DLAT 80
#define NHEAD 8
#define DH 64
#define INNER 512
#define FFD 160
#define DEPTH 24
#define MROWS (BDIM * NNODE)   // 8192

using bf16x8 = __attribute__((ext_vector_type(8))) short;
using f32x4  = __attribute__((ext_vector_type(4))) float;

#define MFMA(a, b, c) __builtin_amdgcn_mfma_f32_16x16x32_bf16((a), (b), (c), 0, 0, 0)

static __device__ __forceinline__ short f2bf(float f) {
    union { float f; unsigned u; } v; v.f = f;
    unsigned r = v.u + 0x7fffu + ((v.u >> 16) & 1u);   // RNE
    return (short)(r >> 16);
}

// ---------------------------------------------------------------------------
// Weight convert + transpose + zero-pad K: out[l][n][kp] = bf16(in[l][k][n])
// k >= K zero-filled up to Kp. grid: (ceil(N/64), ceil(Kp/64), L)
// ---------------------------------------------------------------------------
__global__ __launch_bounds__(256) void wconv_kernel(
    const float* __restrict__ in, short* __restrict__ out, int K, int N, int Kp)
{
    __shared__ float t[64][65];
    int L = blockIdx.z;
    const float* src = in + (size_t)L * K * N;
    short* dst = out + (size_t)L * N * Kp;
    int n0 = blockIdx.x * 64, k0 = blockIdx.y * 64;
    int tx = threadIdx.x & 63, ty = threadIdx.x >> 6;
    for (int ki = ty; ki < 64; ki += 4) {
        int k = k0 + ki, n = n0 + tx;
        t[ki][tx] = (k < K && n < N) ? src[(size_t)k * N + n] : 0.f;
    }
    __syncthreads();
    for (int ni = ty; ni < 64; ni += 4) {
        int n = n0 + ni, k = k0 + tx;
        if (n < N && k < Kp) dst[(size_t)n * Kp + k] = f2bf(t[tx][ni]);
    }
}

// ---------------------------------------------------------------------------
// Graph structural bias
// ---------------------------------------------------------------------------
__global__ __launch_bounds__(256) void bias_kernel(
    const int* __restrict__ spp, const int* __restrict__ ei,
    const float* __restrict__ edge_emb, const float* __restrict__ edw,
    const float* __restrict__ sp_emb, float* __restrict__ biasb)
{
    __shared__ float ee[64], ew[20], se[40];
    int tid = threadIdx.x;
    if (tid < 64) ee[tid] = edge_emb[tid];
    if (tid < 20) ew[tid] = edw[tid];
    if (tid < 40) se[tid] = sp_emb[tid];
    __syncthreads();

    int idx = blockIdx.x * 256 + tid;
    int spv = spp[idx];
    float spb = se[spv];
    int sp = min(20, max(1, spv - 1));

    const int4* p = (const int4*)(ei + (size_t)idx * 60);
    int e[60];
#pragma unroll
    for (int t = 0; t < 15; ++t) {
        int4 v = p[t];
        e[4*t+0] = v.x; e[4*t+1] = v.y; e[4*t+2] = v.z; e[4*t+3] = v.w;
    }
    float acc = 0.f;
#pragma unroll
    for (int m = 0; m < 20; ++m) {
        float s = ee[e[3*m]] + ee[e[3*m+1]] + ee[e[3*m+2]];
        acc += s * ew[m];
    }
    biasb[idx] = acc * (1.0f/3.0f) / (float)sp + spb;
}

// ---------------------------------------------------------------------------
// Node embeddings
// ---------------------------------------------------------------------------
__global__ __launch_bounds__(256) void node_emb_kernel(
    const int* __restrict__ xn, const int* __restrict__ ind, const int* __restrict__ outd,
    const float* __restrict__ ae, const float* __restrict__ ie, const float* __restrict__ oe,
    float* __restrict__ x)
{
    int idx = blockIdx.x * 256 + threadIdx.x;
    int e = idx / DLAT, d = idx % DLAT;
    x[idx] = ae[xn[e]*DLAT + d] + ie[ind[e]*DLAT + d] + oe[outd[e]*DLAT + d];
}

// ---------------------------------------------------------------------------
// Attention kernel: one block per (b, head). 256 threads = 4 waves.
// LN1(all 128 rows) -> Q,K,V (head slice) -> QK^T + bias -> softmax -> PV.
// Grid 512 -> 2 blocks/CU (LDS 80,896 B). 4 barriers.
// LDS (shorts): lnx@0 [128][104]; qh@13312 [128][72]; kh@22528 [128][72];
//               vth@31744 [64][136];  ph@0 [128][136] (aliases lnx+qh)
// ---------------------------------------------------------------------------
__global__ __launch_bounds__(256, 2) void attnfull_kernel(
    const float* __restrict__ xin, const float* __restrict__ biasb,
    const short* __restrict__ Wq_t, const short* __restrict__ Wkv_t,
    const float* __restrict__ g1, const float* __restrict__ be1,
    short* __restrict__ obuf)
{
    extern __shared__ short smem[];
    short* lnx = smem;           // [128][104]
    short* qh  = smem + 13312;   // [128][72]
    short* kh  = smem + 22528;   // [128][72]
    short* vth = smem + 31744;   // [64][136]
    short* ph  = smem;           // [128][136] overlay

    int tid = threadIdx.x;
    int lane = tid & 63, w = tid >> 6, l15 = lane & 15, lk = lane >> 4;
    int b = blockIdx.x >> 3, h = blockIdx.x & 7;
    const float* xb = xin + (size_t)b * NNODE * DLAT;

    // ---- LN1 -> lnx bf16 (2 threads/row) ----
    {
        int row = tid >> 1, sub = tid & 1;
        const float* xr = xb + row * DLAT + sub * 40;
        float4 v[10];
#pragma unroll
        for (int i = 0; i < 10; ++i) v[i] = *(const float4*)(xr + i * 4);
        float s = 0.f;
#pragma unroll
        for (int i = 0; i < 10; ++i) s += v[i].x + v[i].y + v[i].z + v[i].w;
        s += __shfl_xor(s, 1);
        float mean = s * 0.0125f;
        float var = 0.f;
#pragma unroll
        for (int i = 0; i < 10; ++i) {
            float d;
            d = v[i].x - mean; var += d * d;
            d = v[i].y - mean; var += d * d;
            d = v[i].z - mean; var += d * d;
            d = v[i].w - mean; var += d * d;
        }
        var += __shfl_xor(var, 1);
        float rstd = 1.0f / sqrtf(var * 0.0125f + 1e-5f);
        short* dst = lnx + row * 104 + sub * 40;
#pragma unroll
        for (int i = 0; i < 10; ++i) {
            int c = sub * 40 + i * 4;
            float4 g4 = *(const float4*)(g1 + c);
            float4 b4 = *(const float4*)(be1 + c);
            short4 o;
            o.x = f2bf((v[i].x - mean) * rstd * g4.x + b4.x);
            o.y = f2bf((v[i].y - mean) * rstd * g4.y + b4.y);
            o.z = f2bf((v[i].z - mean) * rstd * g4.z + b4.z);
            o.w = f2bf((v[i].w - mean) * rstd * g4.w + b4.w);
            *(short4*)(dst + i * 4) = o;
        }
        short4 z4; z4.x = z4.y = z4.z = z4.w = 0;
        *(short4*)(lnx + row * 104 + 80 + sub * 8) = z4;
        *(short4*)(lnx + row * 104 + 84 + sub * 8) = z4;
    }
    __syncthreads();

    // ---- Q,K,V for this head (wave w: row-frags 2w, 2w+1) ----
    {
        bf16x8 a[2][3];
#pragma unroll
        for (int i = 0; i < 2; ++i)
#pragma unroll
            for (int ss = 0; ss < 3; ++ss)
                a[i][ss] = *(const bf16x8*)(lnx + ((w * 2 + i) * 16 + l15) * 104 + lk * 8 + ss * 32);

        // Q
        {
            f32x4 acc[2][4] = {};
#pragma unroll
            for (int ss = 0; ss < 3; ++ss)
#pragma unroll
                for (int nf = 0; nf < 4; ++nf) {
                    bf16x8 bv = *(const bf16x8*)(Wq_t + (size_t)(h * 64 + nf * 16 + l15) * 96 + lk * 8 + ss * 32);
                    acc[0][nf] = MFMA(a[0][ss], bv, acc[0][nf]);
                    acc[1][nf] = MFMA(a[1][ss], bv, acc[1][nf]);
                }
#pragma unroll
            for (int i = 0; i < 2; ++i)
#pragma unroll
                for (int nf = 0; nf < 4; ++nf)
#pragma unroll
                    for (int r = 0; r < 4; ++r)
                        qh[((w * 2 + i) * 16 + lk * 4 + r) * 72 + nf * 16 + l15] = f2bf(acc[i][nf][r]);
        }
        // K
        {
            f32x4 acc[2][4] = {};
#pragma unroll
            for (int ss = 0; ss < 3; ++ss)
#pragma unroll
                for (int nf = 0; nf < 4; ++nf) {
                    bf16x8 bv = *(const bf16x8*)(Wkv_t + (size_t)(h * 64 + nf * 16 + l15) * 96 + lk * 8 + ss * 32);
                    acc[0][nf] = MFMA(a[0][ss], bv, acc[0][nf]);
                    acc[1][nf] = MFMA(a[1][ss], bv, acc[1][nf]);
                }
#pragma unroll
            for (int i = 0; i < 2; ++i)
#pragma unroll
                for (int nf = 0; nf < 4; ++nf)
#pragma unroll
                    for (int r = 0; r < 4; ++r)
                        kh[((w * 2 + i) * 16 + lk * 4 + r) * 72 + nf * 16 + l15] = f2bf(acc[i][nf][r]);
        }
        // V (store transposed)
        {
            f32x4 acc[2][4] = {};
#pragma unroll
            for (int ss = 0; ss < 3; ++ss)
#pragma unroll
                for (int nf = 0; nf < 4; ++nf) {
                    bf16x8 bv = *(const bf16x8*)(Wkv_t + (size_t)(INNER + h * 64 + nf * 16 + l15) * 96 + lk * 8 + ss * 32);
                    acc[0][nf] = MFMA(a[0][ss], bv, acc[0][nf]);
                    acc[1][nf] = MFMA(a[1][ss], bv, acc[1][nf]);
                }
#pragma unroll
            for (int i = 0; i < 2; ++i)
#pragma unroll
                for (int nf = 0; nf < 4; ++nf)
#pragma unroll
                    for (int r = 0; r < 4; ++r)
                        vth[(nf * 16 + l15) * 136 + (w * 2 + i) * 16 + lk * 4 + r] = f2bf(acc[i][nf][r]);
        }
    }
    __syncthreads();

    // ---- bias prefetch (consumed after QK^T) ----
    float breg[2][8][4];
    {
        const float* bp = biasb + ((size_t)b * NNODE + w * 32) * NNODE;
#pragma unroll
        for (int i = 0; i < 2; ++i)
#pragma unroll
            for (int jf = 0; jf < 8; ++jf)
#pragma unroll
                for (int r = 0; r < 4; ++r)
                    breg[i][jf][r] = bp[(i * 16 + lk * 4 + r) * NNODE + jf * 16 + l15];
    }

    // ---- QK^T ----
    f32x4 sc[2][8] = {};
#pragma unroll
    for (int ss = 0; ss < 2; ++ss) {
        bf16x8 qa0 = *(const bf16x8*)(qh + ((w * 2) * 16 + l15) * 72 + lk * 8 + ss * 32);
        bf16x8 qa1 = *(const bf16x8*)(qh + ((w * 2 + 1) * 16 + l15) * 72 + lk * 8 + ss * 32);
#pragma unroll
        for (int jf = 0; jf < 8; ++jf) {
            bf16x8 bv = *(const bf16x8*)(kh + (jf * 16 + l15) * 72 + lk * 8 + ss * 32);
            sc[0][jf] = MFMA(qa0, bv, sc[0][jf]);
            sc[1][jf] = MFMA(qa1, bv, sc[1][jf]);
        }
    }
    __syncthreads();   // all qh reads done before ph overlay writes

    // ---- softmax (rows owned in regs) + P -> LDS ----
    float rinv[2][4];
#pragma unroll
    for (int i = 0; i < 2; ++i)
#pragma unroll
    for (int r = 0; r < 4; ++r) {
        float sv[8];
#pragma unroll
        for (int jf = 0; jf < 8; ++jf) sv[jf] = sc[i][jf][r] * 0.125f + breg[i][jf][r];
        float mx = sv[0];
#pragma unroll
        for (int jf = 1; jf < 8; ++jf) mx = fmaxf(mx, sv[jf]);
        mx = fmaxf(mx, __shfl_xor(mx, 1));
        mx = fmaxf(mx, __shfl_xor(mx, 2));
        mx = fmaxf(mx, __shfl_xor(mx, 4));
        mx = fmaxf(mx, __shfl_xor(mx, 8));
        float e[8], sum = 0.f;
#pragma unroll
        for (int jf = 0; jf < 8; ++jf) { e[jf] = __expf(sv[jf] - mx); sum += e[jf]; }
        sum += __shfl_xor(sum, 1);
        sum += __shfl_xor(sum, 2);
        sum += __shfl_xor(sum, 4);
        sum += __shfl_xor(sum, 8);
        rinv[i][r] = 1.0f / sum;
        int row = (w * 2 + i) * 16 + lk * 4 + r;
#pragma unroll
        for (int jf = 0; jf < 8; ++jf)
            ph[row * 136 + jf * 16 + l15] = f2bf(e[jf]);
    }
    __syncthreads();

    // ---- PV ----
    f32x4 o[2][4] = {};
#pragma unroll
    for (int ks = 0; ks < 4; ++ks) {
        bf16x8 pa0 = *(const bf16x8*)(ph + ((w * 2) * 16 + l15) * 136 + lk * 8 + ks * 32);
        bf16x8 pa1 = *(const bf16x8*)(ph + ((w * 2 + 1) * 16 + l15) * 136 + lk * 8 + ks * 32);
#pragma unroll
        for (int nf = 0; nf < 4; ++nf) {
            bf16x8 bv = *(const bf16x8*)(vth + (nf * 16 + l15) * 136 + lk * 8 + ks * 32);
            o[0][nf] = MFMA(pa0, bv, o[0][nf]);
            o[1][nf] = MFMA(pa1, bv, o[1][nf]);
        }
    }
#pragma unroll
    for (int i = 0; i < 2; ++i)
#pragma unroll
    for (int nf = 0; nf < 4; ++nf)
#pragma unroll
    for (int r = 0; r < 4; ++r) {
        int row = (w * 2 + i) * 16 + lk * 4 + r;
        obuf[((size_t)b * NNODE + row) * INNER + h * 64 + nf * 16 + l15] =
            f2bf(o[i][nf][r] * rinv[i][r]);
    }
}

// ---------------------------------------------------------------------------
// Tail kernel: one block per (b, quarter), 512 threads = 8 waves (2/SIMD).
// obuf@Wo + bo + resid -> LN2 -> FF1+GELU -> FF2 + b2 + resid -> xout
// Waves: wr = w>>2 (row-frag), wn = w&3 (col group).
// ---------------------------------------------------------------------------
__global__ __launch_bounds__(512, 2) void tail_kernel(
    const short* __restrict__ obuf, const float* __restrict__ xin,
    const short* __restrict__ Wo_t, const float* __restrict__ boL,
    const float* __restrict__ g2, const float* __restrict__ be2,
    const short* __restrict__ W1_t, const float* __restrict__ b1L,
    const short* __restrict__ W2_t, const float* __restrict__ b2L,
    float* __restrict__ xout)
{
    __shared__ short obs[32 * 520];    // 33,280 B
    __shared__ float xmid[32 * 84];    // 10,752 B (pad 84)
    __shared__ short h2s[32 * 104];    //  6,656 B
    __shared__ short ffhs[32 * 168];   // 10,752 B

    int tid = threadIdx.x;
    int lane = tid & 63, w = tid >> 6, l15 = lane & 15, lk = lane >> 4;
    int b = blockIdx.x >> 2, qq = blockIdx.x & 3;
    int R0 = qq * 32;
    int wr = w >> 2, wn = w & 3;

    // stage obuf tile
    {
        int row = tid >> 4, cs = (tid & 15) * 32;
        const short* src = obuf + ((size_t)b * NNODE + R0 + row) * INNER + cs;
        short* dst = obs + row * 520 + cs;
#pragma unroll
        for (int q = 0; q < 4; ++q)
            *(uint4*)(dst + q * 8) = *(const uint4*)(src + q * 8);
    }
    __syncthreads();

    const int st5[4] = {0, 2, 3, 4}, cn5[4] = {2, 1, 1, 1};
    const int st10[4] = {0, 3, 6, 8}, cn10[4] = {3, 3, 2, 2};

    // ---- O-proj + bo + residual -> xmid ----
    {
        int n0 = st5[wn], nc = cn5[wn];
        f32x4 acc[2] = {};
#pragma unroll 4
        for (int ks = 0; ks < 16; ++ks) {
            bf16x8 aa = *(const bf16x8*)(obs + (wr * 16 + l15) * 520 + lk * 8 + ks * 32);
#pragma unroll
            for (int j = 0; j < 2; ++j)
                if (j < nc) {
                    bf16x8 bv = *(const bf16x8*)(Wo_t + (size_t)((n0 + j) * 16 + l15) * INNER + lk * 8 + ks * 32);
                    acc[j] = MFMA(aa, bv, acc[j]);
                }
        }
#pragma unroll
        for (int j = 0; j < 2; ++j)
            if (j < nc)
#pragma unroll
                for (int r = 0; r < 4; ++r) {
                    int row = wr * 16 + lk * 4 + r, col = (n0 + j) * 16 + l15;
                    xmid[row * 84 + col] = acc[j][r] + boL[col] +
                        xin[((size_t)b * NNODE + R0 + row) * DLAT + col];
                }
    }
    __syncthreads();

    // ---- LN2 -> h2s (16 threads/row, 5 elems each) ----
    {
        int row = tid >> 4, sub = tid & 15;
        float v[5];
#pragma unroll
        for (int e = 0; e < 5; ++e) v[e] = xmid[row * 84 + sub * 5 + e];
        float s = v[0] + v[1] + v[2] + v[3] + v[4];
        s += __shfl_xor(s, 1); s += __shfl_xor(s, 2);
        s += __shfl_xor(s, 4); s += __shfl_xor(s, 8);
        float mean = s * 0.0125f;
        float var = 0.f;
#pragma unroll
        for (int e = 0; e < 5; ++e) { float d = v[e] - mean; var += d * d; }
        var += __shfl_xor(var, 1); var += __shfl_xor(var, 2);
        var += __shfl_xor(var, 4); var += __shfl_xor(var, 8);
        float rstd = 1.0f / sqrtf(var * 0.0125f + 1e-5f);
#pragma unroll
        for (int e = 0; e < 5; ++e) {
            int c = sub * 5 + e;
            h2s[row * 104 + c] = f2bf((v[e] - mean) * rstd * g2[c] + be2[c]);
        }
        if (sub < 4) {
            short4 z4; z4.x = z4.y = z4.z = z4.w = 0;
            *(short4*)(h2s + row * 104 + 80 + sub * 4) = z4;
        }
    }
    __syncthreads();

    // ---- FF1 + GELU -> ffhs ----
    {
        int n0 = st10[wn], nc = cn10[wn];
        f32x4 acc[3] = {};
#pragma unroll
        for (int ss = 0; ss < 3; ++ss) {
            bf16x8 aa = *(const bf16x8*)(h2s + (wr * 16 + l15) * 104 + lk * 8 + ss * 32);
#pragma unroll
            for (int j = 0; j < 3; ++j)
                if (j < nc) {
                    bf16x8 bv = *(const bf16x8*)(W1_t + (size_t)((n0 + j) * 16 + l15) * 96 + lk * 8 + ss * 32);
                    acc[j] = MFMA(aa, bv, acc[j]);
                }
        }
#pragma unroll
        for (int j = 0; j < 3; ++j)
            if (j < nc)
#pragma unroll
                for (int r = 0; r < 4; ++r) {
                    int row = wr * 16 + lk * 4 + r, c = (n0 + j) * 16 + l15;
                    float vv = acc[j][r] + b1L[c];
                    vv = 0.5f * vv * (1.0f + erff(vv * 0.70710678118654752f));
                    ffhs[row * 168 + c] = f2bf(vv);
                }
    }
    __syncthreads();

    // ---- FF2 + b2 + residual -> xout ----
    {
        int n0 = st5[wn], nc = cn5[wn];
        f32x4 acc[2] = {};
#pragma unroll
        for (int ks = 0; ks < 5; ++ks) {
            bf16x8 aa = *(const bf16x8*)(ffhs + (wr * 16 + l15) * 168 + lk * 8 + ks * 32);
#pragma unroll
            for (int j = 0; j < 2; ++j)
                if (j < nc) {
                    bf16x8 bv = *(const bf16x8*)(W2_t + (size_t)((n0 + j) * 16 + l15) * FFD + lk * 8 + ks * 32);
                    acc[j] = MFMA(aa, bv, acc[j]);
                }
        }
#pragma unroll
        for (int j = 0; j < 2; ++j)
            if (j < nc)
#pragma unroll
                for (int r = 0; r < 4; ++r) {
                    int row = wr * 16 + lk * 4 + r, col = (n0 + j) * 16 + l15;
                    xout[((size_t)b * NNODE + R0 + row) * DLAT + col] =
                        acc[j][r] + b2L[col] + xmid[row * 84 + col];
                }
    }
}

// ---------------------------------------------------------------------------
// Final: mean over nodes -> LN -> @Wf + bf
// ---------------------------------------------------------------------------
__global__ __launch_bounds__(128) void final_kernel(
    const float* __restrict__ x, const float* __restrict__ g, const float* __restrict__ bta,
    const float* __restrict__ Wf, const float* __restrict__ bf, float* __restrict__ out)
{
    int bb = blockIdx.x;
    int t = threadIdx.x;
    __shared__ float pd[DLAT];
    __shared__ float red[2];
    __shared__ float rbuf[128];

    if (t < DLAT) {
        float s = 0.f;
        for (int n = 0; n < NNODE; ++n) s += x[((size_t)bb * NNODE + n) * DLAT + t];
        pd[t] = s * (1.0f / NNODE);
    }
    __syncthreads();
    if (t == 0) {
        float m = 0.f;
        for (int k = 0; k < DLAT; ++k) m += pd[k];
        m /= DLAT;
        float v = 0.f;
        for (int k = 0; k < DLAT; ++k) { float d = pd[k] - m; v += d * d; }
        v /= DLAT;
        red[0] = m; red[1] = 1.0f / sqrtf(v + 1e-5f);
    }
    __syncthreads();
    float contrib = 0.f;
    if (t < DLAT)
        contrib = ((pd[t] - red[0]) * red[1] * g[t] + bta[t]) * Wf[t];
    rbuf[t] = contrib;
    __syncthreads();
    if (t == 0) {
        float s = 0.f;
        for (int k = 0; k < DLAT; ++k) s += rbuf[k];
        out[bb] = s + bf[0];
    }
}

// ---------------------------------------------------------------------------
extern "C" void kernel_launch(void* const* d_in, const int* in_sizes, int n_in,
                              void* d_out, int out_size, void* d_ws, size_t ws_size,
                              hipStream_t stream)
{
    const int*   spatial_pos = (const int*)  d_in[0];
    const int*   edge_input  = (const int*)  d_in[1];
    const int*   x_nodes     = (const int*)  d_in[2];
    const int*   indeg       = (const int*)  d_in[3];
    const int*   outdeg      = (const int*)  d_in[4];
    const float* atom_emb    = (const float*)d_in[5];
    const float* indeg_emb   = (const float*)d_in[6];
    const float* outdeg_emb  = (const float*)d_in[7];
    const float* edge_emb    = (const float*)d_in[8];
    const float* edge_dis_w  = (const float*)d_in[9];
    const float* spatial_emb = (const float*)d_in[10];
    const float* ln1_g = (const float*)d_in[11];
    const float* ln1_b = (const float*)d_in[12];
    const float* Wq    = (const float*)d_in[13];
    const float* Wkv   = (const float*)d_in[14];
    const float* Wo    = (const float*)d_in[15];
    const float* bo    = (const float*)d_in[16];
    const float* ln2_g = (const float*)d_in[17];
    const float* ln2_b = (const float*)d_in[18];
    const float* W1    = (const float*)d_in[19];
    const float* b1    = (const float*)d_in[20];
    const float* W2    = (const float*)d_in[21];
    const float* b2    = (const float*)d_in[22];
    const float* lnf_g = (const float*)d_in[23];
    const float* lnf_b = (const float*)d_in[24];
    const float* Wf    = (const float*)d_in[25];
    const float* bf    = (const float*)d_in[26];

    char* wsb = (char*)d_ws;
    float* biasb = (float*)(wsb + 0);           //  4,194,304
    float* x0    = (float*)(wsb + 4194304);     //  2,621,440
    float* x1    = (float*)(wsb + 6815744);     //  2,621,440
    short* obuf  = (short*)(wsb + 9437184);     //  8,388,608
    short* Wq_t  = (short*)(wsb + 17825792);    //  2,359,296  [512][96]/layer
    short* Wkv_t = (short*)(wsb + 20185088);    //  4,718,592  [1024][96]/layer
    short* Wo_t  = (short*)(wsb + 24903680);    //  1,966,080  [80][512]/layer
    short* W1_t  = (short*)(wsb + 26869760);    //    737,280  [160][96]/layer
    short* W2_t  = (short*)(wsb + 27607040);    //    614,400  [80][160]/layer

    static const int ATTN_LDS = 80896;
    hipFuncSetAttribute((const void*)attnfull_kernel,
                        hipFuncAttributeMaxDynamicSharedMemorySize, ATTN_LDS);

    wconv_kernel<<<dim3(8, 2, 24), 256, 0, stream>>>(Wq,  Wq_t,  80, 512, 96);
    wconv_kernel<<<dim3(16, 2, 24), 256, 0, stream>>>(Wkv, Wkv_t, 80, 1024, 96);
    wconv_kernel<<<dim3(2, 8, 24), 256, 0, stream>>>(Wo,  Wo_t,  512, 80, 512);
    wconv_kernel<<<dim3(3, 2, 24), 256, 0, stream>>>(W1,  W1_t,  80, 160, 96);
    wconv_kernel<<<dim3(2, 3, 24), 256, 0, stream>>>(W2,  W2_t,  160, 80, 160);

    bias_kernel<<<4096, 256, 0, stream>>>(spatial_pos, edge_input, edge_emb,
                                          edge_dis_w, spatial_emb, biasb);
    node_emb_kernel<<<2560, 256, 0, stream>>>(x_nodes, indeg, outdeg,
                                              atom_emb, indeg_emb, outdeg_emb, x0);

    for (int L = 0; L < DEPTH; ++L) {
        const float* xin  = (L & 1) ? x1 : x0;
        float*       xout = (L & 1) ? x0 : x1;
        attnfull_kernel<<<512, 256, ATTN_LDS, stream>>>(
            xin, biasb,
            Wq_t + (size_t)L * 512 * 96, Wkv_t + (size_t)L * 1024 * 96,
            ln1_g + L * DLAT, ln1_b + L * DLAT, obuf);
        tail_kernel<<<256, 512, 0, stream>>>(
            obuf, xin,
            Wo_t + (size_t)L * 80 * 512, bo + L * DLAT,
            ln2_g + L * DLAT, ln2_b + L * DLAT,
            W1_t + (size_t)L * 160 * 96, b1 + L * FFD,
            W2_t + (size_t)L * 80 * 160, b2 + L * DLAT,
            xout);
    }

    final_kernel<<<BDIM, 128, 0, stream>>>(x0, lnf_g, lnf_b, Wf, bf, (float*)d_out);
}